// Round 1
// 882.453 us; speedup vs baseline: 1.6733x; 1.6733x over previous
//
#include <hip/hip_runtime.h>
#include <math.h>

// ---------------------------------------------------------------------------
// Round 10: attention moved from the f64 MAI pipe (78.6 TF, measured at its
// roofline: 68.7 GF / 914 us = 75 TF) to the f16 MFMA pipe (2382 TF) using a
// Dekker hi/lo split: x = hi + lo (both f16), x*y ~= hi*hi + hi*lo + lo*hi
// (3 MFMAs, dropped lo*lo <= 2^-22*|x||y| -> f32-class precision, matching
// the f32 jax reference).  P is pre-scaled by 512 (exact pow2) to keep its
// lo parts out of the f16 denormal band; divided back out at the end.
// proj epilogue now emits f16 hi/lo planes (Q,K row-major [h][t][d]; V
// pre-transposed [h][d][t] so PV B-frags are contiguous ds_read_b128).
// Softmax: f64 exp() ladder -> f32 __expf.  Barrier skeleton is a verbatim
// port of the green R9 structure.  LDS strides audited: 72 f16 / 68 f32
// give <=2-way conflicts on all hot paths (vs 3.4e7 conflicts in R9).
// Predicted: attn 457 -> ~130-200 us/dispatch, total ~850-950 us.
// ---------------------------------------------------------------------------

typedef _Float16 f16x8 __attribute__((ext_vector_type(8)));
typedef float f32x4 __attribute__((ext_vector_type(4)));
#define MFMA16(a, b, c) __builtin_amdgcn_mfma_f32_16x16x32_f16((a), (b), (c), 0, 0, 0)

// ---------------------------------------------------------------------------
// Kernel 1: per-token abs-max scale (f64 decisions).  UNCHANGED (green).
// ---------------------------------------------------------------------------
__global__ __launch_bounds__(256) void token_scale(
    const float* __restrict__ x0, const float* __restrict__ x1,
    const float* __restrict__ x2, double* __restrict__ out)
{
    const int t = blockIdx.x;
    const int z = blockIdx.y;
    const float* __restrict__ x = (z == 0) ? x0 : ((z == 1) ? x1 : x2);
    const int tid = threadIdx.x;
    float m = 0.0f;
#pragma unroll
    for (int i = 0; i < 2; ++i) {
        int f = i * 256 + tid;
        int b = f >> 7, d4 = f & 127;
        float4 v = *(const float4*)(x + (long)(b * 2048 + t) * 512 + d4 * 4);
        m = fmaxf(m, fmaxf(fmaxf(fabsf(v.x), fabsf(v.y)), fmaxf(fabsf(v.z), fabsf(v.w))));
    }
#pragma unroll
    for (int off = 1; off < 64; off <<= 1) m = fmaxf(m, __shfl_xor(m, off));
    __shared__ float red[4];
    if ((tid & 63) == 0) red[tid >> 6] = m;
    __syncthreads();
    if (tid == 0) {
        m = fmaxf(fmaxf(red[0], red[1]), fmaxf(red[2], red[3]));
        out[z * 2048 + t] = fmax((double)m / 127.0, 1e-8);
    }
}

// ---------------------------------------------------------------------------
// Kernel 2: weight quantization (f64 decisions).  UNCHANGED (green).
// ---------------------------------------------------------------------------
__global__ __launch_bounds__(256) void wquant(
    const float* __restrict__ Wq, const float* __restrict__ Wk,
    const float* __restrict__ Wv, double* __restrict__ sw,
    _Float16* __restrict__ qW)
{
    const int z = blockIdx.y;
    const float* __restrict__ W = (z == 0) ? Wq : (z == 1) ? Wk : Wv;
    const int col = blockIdx.x * 256 + threadIdx.x;
    float m = 0.0f;
    for (int k = 0; k < 512; ++k) m = fmaxf(m, fabsf(W[k * 512 + col]));
    const double s = fmax((double)m / 127.0, 1e-8);
    sw[z * 512 + col] = s;
    _Float16* q = qW + (long)z * 262144 + (long)col * 512;
    for (int k = 0; k < 512; ++k)
        q[k] = (_Float16)fmin(fmax(rint((double)W[k * 512 + col] / s), -128.0), 127.0);
}

// ---------------------------------------------------------------------------
// Kernel 3: projection GEMM (exact-int fp32, f64 decisions + dequant).
// GEMM core unchanged (green); epilogue now emits f16 hi/lo planes.
// Q,K: [h][t][d]; V transposed: [h][d][t] (PV B-frag contiguity).
// ---------------------------------------------------------------------------
__global__ __launch_bounds__(256) void proj_valu(
    const float* __restrict__ q_in, const float* __restrict__ k_in,
    const float* __restrict__ v_in, const double* __restrict__ saAll,
    const _Float16* __restrict__ qW, const double* __restrict__ swAll,
    _Float16* __restrict__ Qh, _Float16* __restrict__ Ql,
    _Float16* __restrict__ Kh, _Float16* __restrict__ Kl,
    _Float16* __restrict__ Vh, _Float16* __restrict__ Vl,
    int b)
{
    const int z = blockIdx.z;
    const float* __restrict__ A = (z == 0) ? q_in : (z == 1) ? k_in : v_in;
    const double* __restrict__ sa = saAll + z * 2048;
    const _Float16* __restrict__ Bq = qW + (long)z * 262144;
    const double* __restrict__ swz = swAll + z * 512;

    const int m0 = blockIdx.x * 64, n0 = blockIdx.y * 64;
    const int tid = threadIdx.x, ty = tid >> 4, tx = tid & 15;

    __shared__ float As[64 * 33];
    __shared__ float Bs[64 * 33];

    float acc[4][4] = {{0.f,0.f,0.f,0.f},{0.f,0.f,0.f,0.f},
                       {0.f,0.f,0.f,0.f},{0.f,0.f,0.f,0.f}};

    for (int k0 = 0; k0 < 512; k0 += 32) {
        if (k0) __syncthreads();
#pragma unroll
        for (int i = 0; i < 2; ++i) {
            int slot = i * 256 + tid;
            int row = slot >> 3, q4 = slot & 7;
            int t = m0 + row;
            float4 v = *(const float4*)(A + ((long)(b * 2048 + t)) * 512 + k0 + q4 * 4);
            double s = sa[t];
            As[row * 33 + q4 * 4 + 0] = (float)fmin(fmax(rint((double)v.x / s), -128.0), 127.0);
            As[row * 33 + q4 * 4 + 1] = (float)fmin(fmax(rint((double)v.y / s), -128.0), 127.0);
            As[row * 33 + q4 * 4 + 2] = (float)fmin(fmax(rint((double)v.z / s), -128.0), 127.0);
            As[row * 33 + q4 * 4 + 3] = (float)fmin(fmax(rint((double)v.w / s), -128.0), 127.0);
            const _Float16* wp = Bq + (long)(n0 + row) * 512 + k0 + q4 * 4;
            Bs[row * 33 + q4 * 4 + 0] = (float)wp[0];
            Bs[row * 33 + q4 * 4 + 1] = (float)wp[1];
            Bs[row * 33 + q4 * 4 + 2] = (float)wp[2];
            Bs[row * 33 + q4 * 4 + 3] = (float)wp[3];
        }
        __syncthreads();
        for (int kk = 0; kk < 32; ++kk) {
            float a[4], bb[4];
#pragma unroll
            for (int i = 0; i < 4; ++i) a[i] = As[(ty * 4 + i) * 33 + kk];
#pragma unroll
            for (int j = 0; j < 4; ++j) bb[j] = Bs[(tx * 4 + j) * 33 + kk];
#pragma unroll
            for (int i = 0; i < 4; ++i)
#pragma unroll
                for (int j = 0; j < 4; ++j) acc[i][j] += a[i] * bb[j];
        }
    }
#pragma unroll
    for (int i = 0; i < 4; ++i)
#pragma unroll
        for (int j = 0; j < 4; ++j) {
            int t = m0 + ty * 4 + i, n = n0 + tx * 4 + j;
            float val = (float)((double)acc[i][j] * sa[t] * swz[n]);
            _Float16 hi = (_Float16)val;
            _Float16 lo = (_Float16)(val - (float)hi);
            int hh = n >> 6, d = n & 63;
            if (z == 2) {
                long idx = ((long)hh * 64 + d) * 2048 + t;     // transposed
                Vh[idx] = hi; Vl[idx] = lo;
            } else if (z == 1) {
                long idx = ((long)hh * 2048 + t) * 64 + d;
                Kh[idx] = hi; Kl[idx] = lo;
            } else {
                long idx = ((long)hh * 2048 + t) * 64 + d;
                Qh[idx] = hi; Ql[idx] = lo;
            }
        }
}

// ---------------------------------------------------------------------------
// Kernel 4: attention on the f16 MFMA pipe, Dekker hi/lo 3-term split.
// grid (32 q-tiles of 64, 8 heads, 2 batch slots), block 256 (4 waves; wave
// w owns q-rows w*16..+15).  K-tile = 64 keys.  A/B frag fill uses the
// standard 16x16x32 mapping (m=lane&15, k=quad*8+j); any k-permutation
// cancels since A and B fills match.  C/D: row=quad*4+r, col=lane&15
// (m89-verified, dtype-independent).
// ---------------------------------------------------------------------------
__global__ __launch_bounds__(256) void attn_mfma(
    const _Float16* __restrict__ Qh0, const _Float16* __restrict__ Ql0,
    const _Float16* __restrict__ Kh0, const _Float16* __restrict__ Kl0,
    const _Float16* __restrict__ Vh0, const _Float16* __restrict__ Vl0,
    float* __restrict__ xbuf, int bbase)
{
    const int q0 = blockIdx.x * 64;
    const int h = blockIdx.y;
    const int slot = blockIdx.z;
    const int b = bbase + slot;
    const long PE = (long)8 * 2048 * 64;
    const _Float16* __restrict__ Qh = Qh0 + (long)slot * PE;
    const _Float16* __restrict__ Ql = Ql0 + (long)slot * PE;
    const _Float16* __restrict__ Kh = Kh0 + (long)slot * PE;
    const _Float16* __restrict__ Kl = Kl0 + (long)slot * PE;
    const _Float16* __restrict__ Vh = Vh0 + (long)slot * PE;
    const _Float16* __restrict__ Vl = Vl0 + (long)slot * PE;

    const int tid = threadIdx.x;
    const int w = tid >> 6, lane = tid & 63;
    const int ln = lane & 15, quad = lane >> 4;

    // LDS: K hi/lo [64 keys][72], V^T hi/lo [64 d][72] (f16, stride 72 =
    // 144B: 16B-aligned, <=2-way banks), S/P [64 q][68] f32 (272B rows).
    __shared__ __align__(16) _Float16 KsH[64 * 72];
    __shared__ __align__(16) _Float16 KsL[64 * 72];
    __shared__ __align__(16) _Float16 VsH[64 * 72];
    __shared__ __align__(16) _Float16 VsL[64 * 72];
    __shared__ __align__(16) float SP[64 * 68];
    __shared__ float mS[64], lS[64], aS[64];
    __shared__ float psums[64 * 4];

    // Q fragments (hi/lo), pinned in registers for the whole kernel.
    f16x8 qh[2], ql[2];
    {
        const long r = ((long)h * 2048 + q0 + w * 16 + ln) * 64 + quad * 8;
        qh[0] = *(const f16x8*)(Qh + r);
        qh[1] = *(const f16x8*)(Qh + r + 32);
        ql[0] = *(const f16x8*)(Ql + r);
        ql[1] = *(const f16x8*)(Ql + r + 32);
    }
    if (tid < 64) { mS[tid] = -INFINITY; lS[tid] = 0.0f; }

    f32x4 O[4];
#pragma unroll
    for (int dt = 0; dt < 4; ++dt) { O[dt][0] = 0; O[dt][1] = 0; O[dt][2] = 0; O[dt][3] = 0; }

    // staging prefetch registers: 2 16B-chunks per plane per thread
    const int srow = tid >> 3, scs = (tid & 7) * 8;
    const long kBase = (long)h * 2048;   // K/Q plane row base (rows = tokens)
    const long vBase = (long)h * 64;     // V^T plane row base (rows = d)
    f16x8 sg0, sg1, sg2, sg3, sg4, sg5, sg6, sg7;
    sg0 = *(const f16x8*)(Kh + (kBase + 0 + srow) * 64 + scs);
    sg1 = *(const f16x8*)(Kh + (kBase + 0 + 32 + srow) * 64 + scs);
    sg2 = *(const f16x8*)(Kl + (kBase + 0 + srow) * 64 + scs);
    sg3 = *(const f16x8*)(Kl + (kBase + 0 + 32 + srow) * 64 + scs);
    sg4 = *(const f16x8*)(Vh + (vBase + srow) * 2048 + 0 + scs);
    sg5 = *(const f16x8*)(Vh + (vBase + 32 + srow) * 2048 + 0 + scs);
    sg6 = *(const f16x8*)(Vl + (vBase + srow) * 2048 + 0 + scs);
    sg7 = *(const f16x8*)(Vl + (vBase + 32 + srow) * 2048 + 0 + scs);

    for (int k0 = 0; k0 < 2048; k0 += 64) {
        __syncthreads();                        // B1: prior readers done
        *(f16x8*)(KsH + srow * 72 + scs)        = sg0;
        *(f16x8*)(KsH + (32 + srow) * 72 + scs) = sg1;
        *(f16x8*)(KsL + srow * 72 + scs)        = sg2;
        *(f16x8*)(KsL + (32 + srow) * 72 + scs) = sg3;
        *(f16x8*)(VsH + srow * 72 + scs)        = sg4;
        *(f16x8*)(VsH + (32 + srow) * 72 + scs) = sg5;
        *(f16x8*)(VsL + srow * 72 + scs)        = sg6;
        *(f16x8*)(VsL + (32 + srow) * 72 + scs) = sg7;
        __syncthreads();                        // B2: tiles visible
        if (k0 + 64 < 2048) {                   // prefetch next tile (hides HBM)
            const int kn = k0 + 64;
            sg0 = *(const f16x8*)(Kh + (kBase + kn + srow) * 64 + scs);
            sg1 = *(const f16x8*)(Kh + (kBase + kn + 32 + srow) * 64 + scs);
            sg2 = *(const f16x8*)(Kl + (kBase + kn + srow) * 64 + scs);
            sg3 = *(const f16x8*)(Kl + (kBase + kn + 32 + srow) * 64 + scs);
            sg4 = *(const f16x8*)(Vh + (vBase + srow) * 2048 + kn + scs);
            sg5 = *(const f16x8*)(Vh + (vBase + 32 + srow) * 2048 + kn + scs);
            sg6 = *(const f16x8*)(Vl + (vBase + srow) * 2048 + kn + scs);
            sg7 = *(const f16x8*)(Vl + (vBase + 32 + srow) * 2048 + kn + scs);
        }

        // ---- S = Q K^T / 8  (4 key-tiles x 2 k-steps x 3 split terms) ----
#pragma unroll
        for (int kt = 0; kt < 4; ++kt) {
            f32x4 s; s[0] = 0; s[1] = 0; s[2] = 0; s[3] = 0;
#pragma unroll
            for (int ks = 0; ks < 2; ++ks) {
                const int off = (kt * 16 + ln) * 72 + ks * 32 + quad * 8;
                f16x8 bh = *(const f16x8*)(KsH + off);
                f16x8 bl = *(const f16x8*)(KsL + off);
                s = MFMA16(ql[ks], bh, s);
                s = MFMA16(qh[ks], bl, s);
                s = MFMA16(qh[ks], bh, s);
            }
#pragma unroll
            for (int r = 0; r < 4; ++r)
                SP[(w * 16 + quad * 4 + r) * 68 + kt * 16 + ln] = s[r] * 0.125f;
        }
        __syncthreads();                        // B3: S visible

        {   // ---- row stats (4 threads/row, stride-4 columns: 2-way banks) ----
            const int row = tid >> 2, c = tid & 3;
            const float* sp = SP + row * 68 + c;
            float rm = -INFINITY;
#pragma unroll
            for (int j = 0; j < 16; ++j) rm = fmaxf(rm, sp[4 * j]);
            rm = fmaxf(rm, __shfl_xor(rm, 1));
            rm = fmaxf(rm, __shfl_xor(rm, 2));
            if (c == 0) {
                float mold = mS[row];
                float mn = fmaxf(mold, rm);
                aS[row] = __expf(mold - mn);
                mS[row] = mn;
            }
        }
        __syncthreads();                        // B4: stats visible

        {   // ---- P = exp(S - m), stored pre-scaled by 512 (exact pow2) ----
            const int row = tid >> 2, c = tid & 3;
            const float mn = mS[row];
            float* sp = SP + row * 68 + c;
            float sum = 0.0f;
#pragma unroll
            for (int j = 0; j < 16; ++j) {
                float p = __expf(sp[4 * j] - mn);
                sum += p;
                sp[4 * j] = p * 512.0f;
            }
            psums[row * 4 + c] = sum;
        }
#pragma unroll
        for (int r = 0; r < 4; ++r) {           // O rescale by exp(m_old-m_new)
            const float a = aS[w * 16 + quad * 4 + r];
#pragma unroll
            for (int dt = 0; dt < 4; ++dt) O[dt][r] *= a;
        }
        __syncthreads();                        // B5: P + psums visible

        if (tid < 64)
            lS[tid] = lS[tid] * aS[tid] +
                      (psums[tid * 4 + 0] + psums[tid * 4 + 1] +
                       psums[tid * 4 + 2] + psums[tid * 4 + 3]);

        // ---- O += P V  (2 key-halves x 4 d-tiles x 3 split terms) ----
#pragma unroll
        for (int ks2 = 0; ks2 < 2; ++ks2) {
            const float* pp = SP + (w * 16 + ln) * 68 + ks2 * 32 + quad * 8;
            f16x8 ph, pl;
#pragma unroll
            for (int j = 0; j < 8; ++j) {
                float p = pp[j];
                _Float16 hi = (_Float16)p;
                ph[j] = hi;
                pl[j] = (_Float16)(p - (float)hi);
            }
#pragma unroll
            for (int dt = 0; dt < 4; ++dt) {
                const int off = (dt * 16 + ln) * 72 + ks2 * 32 + quad * 8;
                f16x8 vh = *(const f16x8*)(VsH + off);
                f16x8 vl = *(const f16x8*)(VsL + off);
                O[dt] = MFMA16(pl, vh, O[dt]);
                O[dt] = MFMA16(ph, vl, O[dt]);
                O[dt] = MFMA16(ph, vh, O[dt]);
            }
        }
    }

    __syncthreads();                            // final lS visible
#pragma unroll
    for (int r = 0; r < 4; ++r) {
        const int row = w * 16 + quad * 4 + r;
        const float inv = 1.0f / (512.0f * lS[row]);   // undo the 512 P-scale
        const long base = ((long)(b * 2048 + q0 + row)) * 512 + h * 64;
#pragma unroll
        for (int dt = 0; dt < 4; ++dt)
            xbuf[base + dt * 16 + ln] = O[dt][r] * inv;
    }
}

// ---------------------------------------------------------------------------
// Kernel 5: final GEMM (f64 decisions, exact-int fp32 GEMM).  UNCHANGED.
// ---------------------------------------------------------------------------
__global__ __launch_bounds__(256) void final_valu(
    const float* __restrict__ xbuf, const double* __restrict__ sx,
    const float* __restrict__ Wf, float* __restrict__ out)
{
    const int m0 = blockIdx.x * 64, n0 = blockIdx.y * 64;
    const int tid = threadIdx.x, ty = tid >> 4, tx = tid & 15;

    __shared__ float As[64 * 33];
    __shared__ float Bs[32 * 65];

    float acc[4][4] = {{0.f,0.f,0.f,0.f},{0.f,0.f,0.f,0.f},
                       {0.f,0.f,0.f,0.f},{0.f,0.f,0.f,0.f}};

    for (int k0 = 0; k0 < 512; k0 += 32) {
        if (k0) __syncthreads();
#pragma unroll
        for (int i = 0; i < 2; ++i) {
            int slot = i * 256 + tid;
            int row = slot >> 3, q4 = slot & 7;
            int m = m0 + row;
            double s = sx[m & 2047];
            float4 v = *(const float4*)(xbuf + (long)m * 512 + k0 + q4 * 4);
            As[row * 33 + q4 * 4 + 0] = (float)fmin(fmax(rint((double)v.x / s), -128.0), 127.0);
            As[row * 33 + q4 * 4 + 1] = (float)fmin(fmax(rint((double)v.y / s), -128.0), 127.0);
            As[row * 33 + q4 * 4 + 2] = (float)fmin(fmax(rint((double)v.z / s), -128.0), 127.0);
            As[row * 33 + q4 * 4 + 3] = (float)fmin(fmax(rint((double)v.w / s), -128.0), 127.0);
            int krow = slot >> 4, n4 = slot & 15;
            float4 w4 = *(const float4*)(Wf + (long)(k0 + krow) * 512 + n0 + n4 * 4);
            Bs[krow * 65 + n4 * 4 + 0] = w4.x;
            Bs[krow * 65 + n4 * 4 + 1] = w4.y;
            Bs[krow * 65 + n4 * 4 + 2] = w4.z;
            Bs[krow * 65 + n4 * 4 + 3] = w4.w;
        }
        __syncthreads();
        for (int kk = 0; kk < 32; ++kk) {
            float a[4], bb[4];
#pragma unroll
            for (int i = 0; i < 4; ++i) a[i] = As[(ty * 4 + i) * 33 + kk];
#pragma unroll
            for (int j = 0; j < 4; ++j) bb[j] = Bs[kk * 65 + tx * 4 + j];
#pragma unroll
            for (int i = 0; i < 4; ++i)
#pragma unroll
                for (int j = 0; j < 4; ++j) acc[i][j] += a[i] * bb[j];
        }
    }
#pragma unroll
    for (int i = 0; i < 4; ++i)
#pragma unroll
        for (int j = 0; j < 4; ++j) {
            int m = m0 + ty * 4 + i, n = n0 + tx * 4 + j;
            out[(long)m * 512 + n] = (float)((double)acc[i][j] * sx[m & 2047]);
        }
}

// ---------------------------------------------------------------------------
extern "C" void kernel_launch(void* const* d_in, const int* in_sizes, int n_in,
                              void* d_out, int out_size, void* d_ws, size_t ws_size,
                              hipStream_t stream)
{
    const float* query = (const float*)d_in[0];
    const float* key_  = (const float*)d_in[1];
    const float* value = (const float*)d_in[2];
    const float* Wq = (const float*)d_in[3];
    const float* Wk = (const float*)d_in[4];
    const float* Wv = (const float*)d_in[5];
    const float* Wf = (const float*)d_in[6];
    float* out = (float*)d_out;

    // workspace carve-up: ~42 MB (down from ~66 MB)
    char* p = (char*)d_ws;
    auto alloc = [&](size_t bytes) -> char* {
        char* r = p;
        p += (bytes + 255) & ~(size_t)255;
        return r;
    };
    double*   sA   = (double*)alloc(3 * 2048 * 8);
    double*   sx   = (double*)alloc(2048 * 8);
    double*   sw   = (double*)alloc(3 * 512 * 8);
    _Float16* qW   = (_Float16*)alloc((size_t)3 * 512 * 512 * 2);
    const long PE  = (long)8 * 2048 * 64;   // halfs per slot-plane (2 MB)
    _Float16* Qh   = (_Float16*)alloc((size_t)2 * PE * 2);
    _Float16* Ql   = (_Float16*)alloc((size_t)2 * PE * 2);
    _Float16* Kh   = (_Float16*)alloc((size_t)2 * PE * 2);
    _Float16* Kl   = (_Float16*)alloc((size_t)2 * PE * 2);
    _Float16* Vh   = (_Float16*)alloc((size_t)2 * PE * 2);
    _Float16* Vl   = (_Float16*)alloc((size_t)2 * PE * 2);
    float*    xbuf = (float*)alloc((size_t)8192 * 512 * 4);

    token_scale<<<dim3(2048, 3), 256, 0, stream>>>(query, key_, value, sA);
    wquant<<<dim3(2, 3), 256, 0, stream>>>(Wq, Wk, Wv, sw, qW);
    for (int pair = 0; pair < 2; ++pair) {
        proj_valu<<<dim3(32, 8, 3), 256, 0, stream>>>(query, key_, value, sA, qW, sw,
            Qh, Ql, Kh, Kl, Vh, Vl, pair * 2);
        proj_valu<<<dim3(32, 8, 3), 256, 0, stream>>>(query, key_, value, sA, qW, sw,
            Qh + PE, Ql + PE, Kh + PE, Kl + PE, Vh + PE, Vl + PE, pair * 2 + 1);
        attn_mfma<<<dim3(32, 8, 2), 256, 0, stream>>>(Qh, Ql, Kh, Kl, Vh, Vl, xbuf, pair * 2);
    }
    token_scale<<<dim3(2048, 1), 256, 0, stream>>>(xbuf, xbuf, xbuf, sx);
    final_valu<<<dim3(128, 8), 256, 0, stream>>>(xbuf, sx, Wf, out);
}

// Round 2
// 741.492 us; speedup vs baseline: 1.9914x; 1.1901x over previous
//
#include <hip/hip_runtime.h>
#include <math.h>

// ---------------------------------------------------------------------------
// Round 11: wquant re-shaped.  R10 moved attention to the f16 MFMA pipe
// (882 us total, absmax 54.0 unchanged); rocprof now shows wquant as the
// slowest dispatch class (~200 us, 0.23% occupancy, 0.2% HBM): grid was 6
// blocks, and each thread issued 512 strided 2-byte global writes.  New
// wquant: 24 blocks x 256 threads, coalesced row-major reads, LDS-staged
// transpose, coalesced 256B-chunk writes of the column-major qW.  Math is
// bit-identical (same f64 scale decision, same rint/clamp), so absmax is
// provably unchanged.  All other kernels byte-identical to green R10.
// Predicted: wquant ~200 -> ~10 us; total 882 -> ~700 us.
// ---------------------------------------------------------------------------

typedef _Float16 f16x8 __attribute__((ext_vector_type(8)));
typedef float f32x4 __attribute__((ext_vector_type(4)));
#define MFMA16(a, b, c) __builtin_amdgcn_mfma_f32_16x16x32_f16((a), (b), (c), 0, 0, 0)

// ---------------------------------------------------------------------------
// Kernel 1: per-token abs-max scale (f64 decisions).  UNCHANGED (green).
// ---------------------------------------------------------------------------
__global__ __launch_bounds__(256) void token_scale(
    const float* __restrict__ x0, const float* __restrict__ x1,
    const float* __restrict__ x2, double* __restrict__ out)
{
    const int t = blockIdx.x;
    const int z = blockIdx.y;
    const float* __restrict__ x = (z == 0) ? x0 : ((z == 1) ? x1 : x2);
    const int tid = threadIdx.x;
    float m = 0.0f;
#pragma unroll
    for (int i = 0; i < 2; ++i) {
        int f = i * 256 + tid;
        int b = f >> 7, d4 = f & 127;
        float4 v = *(const float4*)(x + (long)(b * 2048 + t) * 512 + d4 * 4);
        m = fmaxf(m, fmaxf(fmaxf(fabsf(v.x), fabsf(v.y)), fmaxf(fabsf(v.z), fabsf(v.w))));
    }
#pragma unroll
    for (int off = 1; off < 64; off <<= 1) m = fmaxf(m, __shfl_xor(m, off));
    __shared__ float red[4];
    if ((tid & 63) == 0) red[tid >> 6] = m;
    __syncthreads();
    if (tid == 0) {
        m = fmaxf(fmaxf(red[0], red[1]), fmaxf(red[2], red[3]));
        out[z * 2048 + t] = fmax((double)m / 127.0, 1e-8);
    }
}

// ---------------------------------------------------------------------------
// Kernel 2: weight quantization.  RE-SHAPED this round (math bit-identical).
// Grid (8, 3): each block owns 64 columns.  Phase 1: coalesced row-major
// reads, 4 k-groups/column, LDS max-reduce -> f64 scale (same decision
// sequence as before).  Phase 2: quantize into an LDS tile (re-reads W from
// L2).  Phase 3: coalesced transposed write-out, 4 threads/column x 128
// contiguous f16 each (f16x8 chunks).
// ---------------------------------------------------------------------------
__global__ __launch_bounds__(256) void wquant(
    const float* __restrict__ Wq, const float* __restrict__ Wk,
    const float* __restrict__ Wv, double* __restrict__ sw,
    _Float16* __restrict__ qW)
{
    const int z = blockIdx.y;
    const float* __restrict__ W = (z == 0) ? Wq : (z == 1) ? Wk : Wv;
    const int col0 = blockIdx.x * 64;
    const int tid = threadIdx.x;
    const int c = tid & 63, kg = tid >> 6;       // 64 cols x 4 k-groups

    __shared__ float redm[4][64];
    __shared__ double sS[64];
    __shared__ __align__(16) _Float16 qs[64][520];   // 520 f16 = 1040B rows (16B-aligned)

    // phase 1: per-column abs-max (reads coalesced: wave = 64 consecutive cols)
    float m = 0.0f;
    for (int k = kg; k < 512; k += 4)
        m = fmaxf(m, fabsf(W[k * 512 + col0 + c]));
    redm[kg][c] = m;
    __syncthreads();
    if (tid < 64) {
        float mm = fmaxf(fmaxf(redm[0][tid], redm[1][tid]),
                         fmaxf(redm[2][tid], redm[3][tid]));
        double s = fmax((double)mm / 127.0, 1e-8);   // identical f64 decision
        sw[z * 512 + col0 + tid] = s;
        sS[tid] = s;
    }
    __syncthreads();

    // phase 2: quantize into LDS tile (W re-read hits L2)
    const double s = sS[c];
    for (int k = kg; k < 512; k += 4)
        qs[c][k] = (_Float16)fmin(fmax(rint((double)W[k * 512 + col0 + c] / s), -128.0), 127.0);
    __syncthreads();

    // phase 3: coalesced transposed write-out (col-major qW, 256B/thread-chunk)
    const int wc = tid >> 2, kc = (tid & 3) * 128;
    _Float16* q = qW + (long)z * 262144 + (long)(col0 + wc) * 512 + kc;
#pragma unroll
    for (int j = 0; j < 16; ++j)
        *(f16x8*)(q + j * 8) = *(const f16x8*)(&qs[wc][kc + j * 8]);
}

// ---------------------------------------------------------------------------
// Kernel 3: projection GEMM (exact-int fp32, f64 decisions + dequant).
// UNCHANGED (green).  Epilogue emits f16 hi/lo planes; V transposed.
// ---------------------------------------------------------------------------
__global__ __launch_bounds__(256) void proj_valu(
    const float* __restrict__ q_in, const float* __restrict__ k_in,
    const float* __restrict__ v_in, const double* __restrict__ saAll,
    const _Float16* __restrict__ qW, const double* __restrict__ swAll,
    _Float16* __restrict__ Qh, _Float16* __restrict__ Ql,
    _Float16* __restrict__ Kh, _Float16* __restrict__ Kl,
    _Float16* __restrict__ Vh, _Float16* __restrict__ Vl,
    int b)
{
    const int z = blockIdx.z;
    const float* __restrict__ A = (z == 0) ? q_in : (z == 1) ? k_in : v_in;
    const double* __restrict__ sa = saAll + z * 2048;
    const _Float16* __restrict__ Bq = qW + (long)z * 262144;
    const double* __restrict__ swz = swAll + z * 512;

    const int m0 = blockIdx.x * 64, n0 = blockIdx.y * 64;
    const int tid = threadIdx.x, ty = tid >> 4, tx = tid & 15;

    __shared__ float As[64 * 33];
    __shared__ float Bs[64 * 33];

    float acc[4][4] = {{0.f,0.f,0.f,0.f},{0.f,0.f,0.f,0.f},
                       {0.f,0.f,0.f,0.f},{0.f,0.f,0.f,0.f}};

    for (int k0 = 0; k0 < 512; k0 += 32) {
        if (k0) __syncthreads();
#pragma unroll
        for (int i = 0; i < 2; ++i) {
            int slot = i * 256 + tid;
            int row = slot >> 3, q4 = slot & 7;
            int t = m0 + row;
            float4 v = *(const float4*)(A + ((long)(b * 2048 + t)) * 512 + k0 + q4 * 4);
            double s = sa[t];
            As[row * 33 + q4 * 4 + 0] = (float)fmin(fmax(rint((double)v.x / s), -128.0), 127.0);
            As[row * 33 + q4 * 4 + 1] = (float)fmin(fmax(rint((double)v.y / s), -128.0), 127.0);
            As[row * 33 + q4 * 4 + 2] = (float)fmin(fmax(rint((double)v.z / s), -128.0), 127.0);
            As[row * 33 + q4 * 4 + 3] = (float)fmin(fmax(rint((double)v.w / s), -128.0), 127.0);
            const _Float16* wp = Bq + (long)(n0 + row) * 512 + k0 + q4 * 4;
            Bs[row * 33 + q4 * 4 + 0] = (float)wp[0];
            Bs[row * 33 + q4 * 4 + 1] = (float)wp[1];
            Bs[row * 33 + q4 * 4 + 2] = (float)wp[2];
            Bs[row * 33 + q4 * 4 + 3] = (float)wp[3];
        }
        __syncthreads();
        for (int kk = 0; kk < 32; ++kk) {
            float a[4], bb[4];
#pragma unroll
            for (int i = 0; i < 4; ++i) a[i] = As[(ty * 4 + i) * 33 + kk];
#pragma unroll
            for (int j = 0; j < 4; ++j) bb[j] = Bs[(tx * 4 + j) * 33 + kk];
#pragma unroll
            for (int i = 0; i < 4; ++i)
#pragma unroll
                for (int j = 0; j < 4; ++j) acc[i][j] += a[i] * bb[j];
        }
    }
#pragma unroll
    for (int i = 0; i < 4; ++i)
#pragma unroll
        for (int j = 0; j < 4; ++j) {
            int t = m0 + ty * 4 + i, n = n0 + tx * 4 + j;
            float val = (float)((double)acc[i][j] * sa[t] * swz[n]);
            _Float16 hi = (_Float16)val;
            _Float16 lo = (_Float16)(val - (float)hi);
            int hh = n >> 6, d = n & 63;
            if (z == 2) {
                long idx = ((long)hh * 64 + d) * 2048 + t;     // transposed
                Vh[idx] = hi; Vl[idx] = lo;
            } else if (z == 1) {
                long idx = ((long)hh * 2048 + t) * 64 + d;
                Kh[idx] = hi; Kl[idx] = lo;
            } else {
                long idx = ((long)hh * 2048 + t) * 64 + d;
                Qh[idx] = hi; Ql[idx] = lo;
            }
        }
}

// ---------------------------------------------------------------------------
// Kernel 4: attention on the f16 MFMA pipe, Dekker hi/lo 3-term split.
// UNCHANGED (green).
// ---------------------------------------------------------------------------
__global__ __launch_bounds__(256) void attn_mfma(
    const _Float16* __restrict__ Qh0, const _Float16* __restrict__ Ql0,
    const _Float16* __restrict__ Kh0, const _Float16* __restrict__ Kl0,
    const _Float16* __restrict__ Vh0, const _Float16* __restrict__ Vl0,
    float* __restrict__ xbuf, int bbase)
{
    const int q0 = blockIdx.x * 64;
    const int h = blockIdx.y;
    const int slot = blockIdx.z;
    const int b = bbase + slot;
    const long PE = (long)8 * 2048 * 64;
    const _Float16* __restrict__ Qh = Qh0 + (long)slot * PE;
    const _Float16* __restrict__ Ql = Ql0 + (long)slot * PE;
    const _Float16* __restrict__ Kh = Kh0 + (long)slot * PE;
    const _Float16* __restrict__ Kl = Kl0 + (long)slot * PE;
    const _Float16* __restrict__ Vh = Vh0 + (long)slot * PE;
    const _Float16* __restrict__ Vl = Vl0 + (long)slot * PE;

    const int tid = threadIdx.x;
    const int w = tid >> 6, lane = tid & 63;
    const int ln = lane & 15, quad = lane >> 4;

    __shared__ __align__(16) _Float16 KsH[64 * 72];
    __shared__ __align__(16) _Float16 KsL[64 * 72];
    __shared__ __align__(16) _Float16 VsH[64 * 72];
    __shared__ __align__(16) _Float16 VsL[64 * 72];
    __shared__ __align__(16) float SP[64 * 68];
    __shared__ float mS[64], lS[64], aS[64];
    __shared__ float psums[64 * 4];

    // Q fragments (hi/lo), pinned in registers for the whole kernel.
    f16x8 qh[2], ql[2];
    {
        const long r = ((long)h * 2048 + q0 + w * 16 + ln) * 64 + quad * 8;
        qh[0] = *(const f16x8*)(Qh + r);
        qh[1] = *(const f16x8*)(Qh + r + 32);
        ql[0] = *(const f16x8*)(Ql + r);
        ql[1] = *(const f16x8*)(Ql + r + 32);
    }
    if (tid < 64) { mS[tid] = -INFINITY; lS[tid] = 0.0f; }

    f32x4 O[4];
#pragma unroll
    for (int dt = 0; dt < 4; ++dt) { O[dt][0] = 0; O[dt][1] = 0; O[dt][2] = 0; O[dt][3] = 0; }

    // staging prefetch registers: 2 16B-chunks per plane per thread
    const int srow = tid >> 3, scs = (tid & 7) * 8;
    const long kBase = (long)h * 2048;   // K/Q plane row base (rows = tokens)
    const long vBase = (long)h * 64;     // V^T plane row base (rows = d)
    f16x8 sg0, sg1, sg2, sg3, sg4, sg5, sg6, sg7;
    sg0 = *(const f16x8*)(Kh + (kBase + 0 + srow) * 64 + scs);
    sg1 = *(const f16x8*)(Kh + (kBase + 0 + 32 + srow) * 64 + scs);
    sg2 = *(const f16x8*)(Kl + (kBase + 0 + srow) * 64 + scs);
    sg3 = *(const f16x8*)(Kl + (kBase + 0 + 32 + srow) * 64 + scs);
    sg4 = *(const f16x8*)(Vh + (vBase + srow) * 2048 + 0 + scs);
    sg5 = *(const f16x8*)(Vh + (vBase + 32 + srow) * 2048 + 0 + scs);
    sg6 = *(const f16x8*)(Vl + (vBase + srow) * 2048 + 0 + scs);
    sg7 = *(const f16x8*)(Vl + (vBase + 32 + srow) * 2048 + 0 + scs);

    for (int k0 = 0; k0 < 2048; k0 += 64) {
        __syncthreads();                        // B1: prior readers done
        *(f16x8*)(KsH + srow * 72 + scs)        = sg0;
        *(f16x8*)(KsH + (32 + srow) * 72 + scs) = sg1;
        *(f16x8*)(KsL + srow * 72 + scs)        = sg2;
        *(f16x8*)(KsL + (32 + srow) * 72 + scs) = sg3;
        *(f16x8*)(VsH + srow * 72 + scs)        = sg4;
        *(f16x8*)(VsH + (32 + srow) * 72 + scs) = sg5;
        *(f16x8*)(VsL + srow * 72 + scs)        = sg6;
        *(f16x8*)(VsL + (32 + srow) * 72 + scs) = sg7;
        __syncthreads();                        // B2: tiles visible
        if (k0 + 64 < 2048) {                   // prefetch next tile (hides HBM)
            const int kn = k0 + 64;
            sg0 = *(const f16x8*)(Kh + (kBase + kn + srow) * 64 + scs);
            sg1 = *(const f16x8*)(Kh + (kBase + kn + 32 + srow) * 64 + scs);
            sg2 = *(const f16x8*)(Kl + (kBase + kn + srow) * 64 + scs);
            sg3 = *(const f16x8*)(Kl + (kBase + kn + 32 + srow) * 64 + scs);
            sg4 = *(const f16x8*)(Vh + (vBase + srow) * 2048 + kn + scs);
            sg5 = *(const f16x8*)(Vh + (vBase + 32 + srow) * 2048 + kn + scs);
            sg6 = *(const f16x8*)(Vl + (vBase + srow) * 2048 + kn + scs);
            sg7 = *(const f16x8*)(Vl + (vBase + 32 + srow) * 2048 + kn + scs);
        }

        // ---- S = Q K^T / 8  (4 key-tiles x 2 k-steps x 3 split terms) ----
#pragma unroll
        for (int kt = 0; kt < 4; ++kt) {
            f32x4 s; s[0] = 0; s[1] = 0; s[2] = 0; s[3] = 0;
#pragma unroll
            for (int ks = 0; ks < 2; ++ks) {
                const int off = (kt * 16 + ln) * 72 + ks * 32 + quad * 8;
                f16x8 bh = *(const f16x8*)(KsH + off);
                f16x8 bl = *(const f16x8*)(KsL + off);
                s = MFMA16(ql[ks], bh, s);
                s = MFMA16(qh[ks], bl, s);
                s = MFMA16(qh[ks], bh, s);
            }
#pragma unroll
            for (int r = 0; r < 4; ++r)
                SP[(w * 16 + quad * 4 + r) * 68 + kt * 16 + ln] = s[r] * 0.125f;
        }
        __syncthreads();                        // B3: S visible

        {   // ---- row stats (4 threads/row, stride-4 columns: 2-way banks) ----
            const int row = tid >> 2, c = tid & 3;
            const float* sp = SP + row * 68 + c;
            float rm = -INFINITY;
#pragma unroll
            for (int j = 0; j < 16; ++j) rm = fmaxf(rm, sp[4 * j]);
            rm = fmaxf(rm, __shfl_xor(rm, 1));
            rm = fmaxf(rm, __shfl_xor(rm, 2));
            if (c == 0) {
                float mold = mS[row];
                float mn = fmaxf(mold, rm);
                aS[row] = __expf(mold - mn);
                mS[row] = mn;
            }
        }
        __syncthreads();                        // B4: stats visible

        {   // ---- P = exp(S - m), stored pre-scaled by 512 (exact pow2) ----
            const int row = tid >> 2, c = tid & 3;
            const float mn = mS[row];
            float* sp = SP + row * 68 + c;
            float sum = 0.0f;
#pragma unroll
            for (int j = 0; j < 16; ++j) {
                float p = __expf(sp[4 * j] - mn);
                sum += p;
                sp[4 * j] = p * 512.0f;
            }
            psums[row * 4 + c] = sum;
        }
#pragma unroll
        for (int r = 0; r < 4; ++r) {           // O rescale by exp(m_old-m_new)
            const float a = aS[w * 16 + quad * 4 + r];
#pragma unroll
            for (int dt = 0; dt < 4; ++dt) O[dt][r] *= a;
        }
        __syncthreads();                        // B5: P + psums visible

        if (tid < 64)
            lS[tid] = lS[tid] * aS[tid] +
                      (psums[tid * 4 + 0] + psums[tid * 4 + 1] +
                       psums[tid * 4 + 2] + psums[tid * 4 + 3]);

        // ---- O += P V  (2 key-halves x 4 d-tiles x 3 split terms) ----
#pragma unroll
        for (int ks2 = 0; ks2 < 2; ++ks2) {
            const float* pp = SP + (w * 16 + ln) * 68 + ks2 * 32 + quad * 8;
            f16x8 ph, pl;
#pragma unroll
            for (int j = 0; j < 8; ++j) {
                float p = pp[j];
                _Float16 hi = (_Float16)p;
                ph[j] = hi;
                pl[j] = (_Float16)(p - (float)hi);
            }
#pragma unroll
            for (int dt = 0; dt < 4; ++dt) {
                const int off = (dt * 16 + ln) * 72 + ks2 * 32 + quad * 8;
                f16x8 vh = *(const f16x8*)(VsH + off);
                f16x8 vl = *(const f16x8*)(VsL + off);
                O[dt] = MFMA16(pl, vh, O[dt]);
                O[dt] = MFMA16(ph, vl, O[dt]);
                O[dt] = MFMA16(ph, vh, O[dt]);
            }
        }
    }

    __syncthreads();                            // final lS visible
#pragma unroll
    for (int r = 0; r < 4; ++r) {
        const int row = w * 16 + quad * 4 + r;
        const float inv = 1.0f / (512.0f * lS[row]);   // undo the 512 P-scale
        const long base = ((long)(b * 2048 + q0 + row)) * 512 + h * 64;
#pragma unroll
        for (int dt = 0; dt < 4; ++dt)
            xbuf[base + dt * 16 + ln] = O[dt][r] * inv;
    }
}

// ---------------------------------------------------------------------------
// Kernel 5: final GEMM (f64 decisions, exact-int fp32 GEMM).  UNCHANGED.
// ---------------------------------------------------------------------------
__global__ __launch_bounds__(256) void final_valu(
    const float* __restrict__ xbuf, const double* __restrict__ sx,
    const float* __restrict__ Wf, float* __restrict__ out)
{
    const int m0 = blockIdx.x * 64, n0 = blockIdx.y * 64;
    const int tid = threadIdx.x, ty = tid >> 4, tx = tid & 15;

    __shared__ float As[64 * 33];
    __shared__ float Bs[32 * 65];

    float acc[4][4] = {{0.f,0.f,0.f,0.f},{0.f,0.f,0.f,0.f},
                       {0.f,0.f,0.f,0.f},{0.f,0.f,0.f,0.f}};

    for (int k0 = 0; k0 < 512; k0 += 32) {
        if (k0) __syncthreads();
#pragma unroll
        for (int i = 0; i < 2; ++i) {
            int slot = i * 256 + tid;
            int row = slot >> 3, q4 = slot & 7;
            int m = m0 + row;
            double s = sx[m & 2047];
            float4 v = *(const float4*)(xbuf + (long)m * 512 + k0 + q4 * 4);
            As[row * 33 + q4 * 4 + 0] = (float)fmin(fmax(rint((double)v.x / s), -128.0), 127.0);
            As[row * 33 + q4 * 4 + 1] = (float)fmin(fmax(rint((double)v.y / s), -128.0), 127.0);
            As[row * 33 + q4 * 4 + 2] = (float)fmin(fmax(rint((double)v.z / s), -128.0), 127.0);
            As[row * 33 + q4 * 4 + 3] = (float)fmin(fmax(rint((double)v.w / s), -128.0), 127.0);
            int krow = slot >> 4, n4 = slot & 15;
            float4 w4 = *(const float4*)(Wf + (long)(k0 + krow) * 512 + n0 + n4 * 4);
            Bs[krow * 65 + n4 * 4 + 0] = w4.x;
            Bs[krow * 65 + n4 * 4 + 1] = w4.y;
            Bs[krow * 65 + n4 * 4 + 2] = w4.z;
            Bs[krow * 65 + n4 * 4 + 3] = w4.w;
        }
        __syncthreads();
        for (int kk = 0; kk < 32; ++kk) {
            float a[4], bb[4];
#pragma unroll
            for (int i = 0; i < 4; ++i) a[i] = As[(ty * 4 + i) * 33 + kk];
#pragma unroll
            for (int j = 0; j < 4; ++j) bb[j] = Bs[kk * 65 + tx * 4 + j];
#pragma unroll
            for (int i = 0; i < 4; ++i)
#pragma unroll
                for (int j = 0; j < 4; ++j) acc[i][j] += a[i] * bb[j];
        }
    }
#pragma unroll
    for (int i = 0; i < 4; ++i)
#pragma unroll
        for (int j = 0; j < 4; ++j) {
            int m = m0 + ty * 4 + i, n = n0 + tx * 4 + j;
            out[(long)m * 512 + n] = (float)((double)acc[i][j] * sx[m & 2047]);
        }
}

// ---------------------------------------------------------------------------
extern "C" void kernel_launch(void* const* d_in, const int* in_sizes, int n_in,
                              void* d_out, int out_size, void* d_ws, size_t ws_size,
                              hipStream_t stream)
{
    const float* query = (const float*)d_in[0];
    const float* key_  = (const float*)d_in[1];
    const float* value = (const float*)d_in[2];
    const float* Wq = (const float*)d_in[3];
    const float* Wk = (const float*)d_in[4];
    const float* Wv = (const float*)d_in[5];
    const float* Wf = (const float*)d_in[6];
    float* out = (float*)d_out;

    // workspace carve-up: ~42 MB
    char* p = (char*)d_ws;
    auto alloc = [&](size_t bytes) -> char* {
        char* r = p;
        p += (bytes + 255) & ~(size_t)255;
        return r;
    };
    double*   sA   = (double*)alloc(3 * 2048 * 8);
    double*   sx   = (double*)alloc(2048 * 8);
    double*   sw   = (double*)alloc(3 * 512 * 8);
    _Float16* qW   = (_Float16*)alloc((size_t)3 * 512 * 512 * 2);
    const long PE  = (long)8 * 2048 * 64;   // halfs per slot-plane (2 MB)
    _Float16* Qh   = (_Float16*)alloc((size_t)2 * PE * 2);
    _Float16* Ql   = (_Float16*)alloc((size_t)2 * PE * 2);
    _Float16* Kh   = (_Float16*)alloc((size_t)2 * PE * 2);
    _Float16* Kl   = (_Float16*)alloc((size_t)2 * PE * 2);
    _Float16* Vh   = (_Float16*)alloc((size_t)2 * PE * 2);
    _Float16* Vl   = (_Float16*)alloc((size_t)2 * PE * 2);
    float*    xbuf = (float*)alloc((size_t)8192 * 512 * 4);

    token_scale<<<dim3(2048, 3), 256, 0, stream>>>(query, key_, value, sA);
    wquant<<<dim3(8, 3), 256, 0, stream>>>(Wq, Wk, Wv, sw, qW);
    for (int pair = 0; pair < 2; ++pair) {
        proj_valu<<<dim3(32, 8, 3), 256, 0, stream>>>(query, key_, value, sA, qW, sw,
            Qh, Ql, Kh, Kl, Vh, Vl, pair * 2);
        proj_valu<<<dim3(32, 8, 3), 256, 0, stream>>>(query, key_, value, sA, qW, sw,
            Qh + PE, Ql + PE, Kh + PE, Kl + PE, Vh + PE, Vl + PE, pair * 2 + 1);
        attn_mfma<<<dim3(32, 8, 2), 256, 0, stream>>>(Qh, Ql, Kh, Kl, Vh, Vl, xbuf, pair * 2);
    }
    token_scale<<<dim3(2048, 1), 256, 0, stream>>>(xbuf, xbuf, xbuf, sx);
    final_valu<<<dim3(128, 8), 256, 0, stream>>>(xbuf, sx, Wf, out);
}

// Round 3
// 441.606 us; speedup vs baseline: 3.3437x; 1.6791x over previous
//
#include <hip/hip_runtime.h>
#include <math.h>

// ---------------------------------------------------------------------------
// Round 12: both VALU GEMMs (proj_valu ~90us x4, final_valu 110us, 39 TF on
// the 157 TF vector pipe, MfmaUtil=0) move to the f16 MFMA pipe.
//   proj: both operands are quantized ints in [-128,127] -> exact in f16;
//         f32 MFMA accum exact (sums <= 8.26M < 2^24) -> BIT-IDENTICAL output.
//   final: A integer-exact in f16; Wf Dekker hi/lo split (residual 2^-22).
// Quantization hoisted out of the GEMMs (was redone 8x per row) into flat
// coalesced aquant kernels producing f16 int planes; one-shot wfsplit
// transposes+splits Wf.  GEMMs reuse the HW-verified R10 fragment pattern
// (stride-72 LDS, reg-prefetched staging, MFMA16 A-row=ln / D-row=quad*4+r).
// f64 quant decision paths unchanged everywhere -> absmax stays 54.0.
// Predicted: final 110 -> ~18us, proj 4x90 -> 4x15us, total 741 -> ~420us.
// ---------------------------------------------------------------------------

typedef _Float16 f16x8 __attribute__((ext_vector_type(8)));
typedef float f32x4 __attribute__((ext_vector_type(4)));
#define MFMA16(a, b, c) __builtin_amdgcn_mfma_f32_16x16x32_f16((a), (b), (c), 0, 0, 0)

// ---------------------------------------------------------------------------
// Kernel 1: per-token abs-max scale (f64 decisions).  UNCHANGED (green).
// ---------------------------------------------------------------------------
__global__ __launch_bounds__(256) void token_scale(
    const float* __restrict__ x0, const float* __restrict__ x1,
    const float* __restrict__ x2, double* __restrict__ out)
{
    const int t = blockIdx.x;
    const int z = blockIdx.y;
    const float* __restrict__ x = (z == 0) ? x0 : ((z == 1) ? x1 : x2);
    const int tid = threadIdx.x;
    float m = 0.0f;
#pragma unroll
    for (int i = 0; i < 2; ++i) {
        int f = i * 256 + tid;
        int b = f >> 7, d4 = f & 127;
        float4 v = *(const float4*)(x + (long)(b * 2048 + t) * 512 + d4 * 4);
        m = fmaxf(m, fmaxf(fmaxf(fabsf(v.x), fabsf(v.y)), fmaxf(fabsf(v.z), fabsf(v.w))));
    }
#pragma unroll
    for (int off = 1; off < 64; off <<= 1) m = fmaxf(m, __shfl_xor(m, off));
    __shared__ float red[4];
    if ((tid & 63) == 0) red[tid >> 6] = m;
    __syncthreads();
    if (tid == 0) {
        m = fmaxf(fmaxf(red[0], red[1]), fmaxf(red[2], red[3]));
        out[z * 2048 + t] = fmax((double)m / 127.0, 1e-8);
    }
}

// ---------------------------------------------------------------------------
// Kernel 2: weight quantization.  UNCHANGED (green R11).
// ---------------------------------------------------------------------------
__global__ __launch_bounds__(256) void wquant(
    const float* __restrict__ Wq, const float* __restrict__ Wk,
    const float* __restrict__ Wv, double* __restrict__ sw,
    _Float16* __restrict__ qW)
{
    const int z = blockIdx.y;
    const float* __restrict__ W = (z == 0) ? Wq : (z == 1) ? Wk : Wv;
    const int col0 = blockIdx.x * 64;
    const int tid = threadIdx.x;
    const int c = tid & 63, kg = tid >> 6;

    __shared__ float redm[4][64];
    __shared__ double sS[64];
    __shared__ __align__(16) _Float16 qs[64][520];

    float m = 0.0f;
    for (int k = kg; k < 512; k += 4)
        m = fmaxf(m, fabsf(W[k * 512 + col0 + c]));
    redm[kg][c] = m;
    __syncthreads();
    if (tid < 64) {
        float mm = fmaxf(fmaxf(redm[0][tid], redm[1][tid]),
                         fmaxf(redm[2][tid], redm[3][tid]));
        double s = fmax((double)mm / 127.0, 1e-8);
        sw[z * 512 + col0 + tid] = s;
        sS[tid] = s;
    }
    __syncthreads();

    const double s = sS[c];
    for (int k = kg; k < 512; k += 4)
        qs[c][k] = (_Float16)fmin(fmax(rint((double)W[k * 512 + col0 + c] / s), -128.0), 127.0);
    __syncthreads();

    const int wc = tid >> 2, kc = (tid & 3) * 128;
    _Float16* q = qW + (long)z * 262144 + (long)(col0 + wc) * 512 + kc;
#pragma unroll
    for (int j = 0; j < 16; ++j)
        *(f16x8*)(q + j * 8) = *(const f16x8*)(&qs[wc][kc + j * 8]);
}

// ---------------------------------------------------------------------------
// Kernel 2b: activation quantization into f16 int planes (f64 decisions,
// identical rint/clamp sequence -> same integers as the old in-GEMM quant).
// Works for q/k/v (grid (2048,3), scales sA) and xbuf (grid (2048,1), sx):
// plane count 4*2048*512 == 8192*512, and t = (f>>9)&2047 in both layouts.
// ---------------------------------------------------------------------------
__global__ __launch_bounds__(256) void aquant(
    const float* __restrict__ x0, const float* __restrict__ x1,
    const float* __restrict__ x2, const double* __restrict__ sAll,
    _Float16* __restrict__ qA)
{
    const int z = blockIdx.y;
    const float* __restrict__ x = (z == 0) ? x0 : ((z == 1) ? x1 : x2);
    const double* __restrict__ s = sAll + z * 2048;
    const long PLANE = (long)4 * 2048 * 512;
    const long f = ((long)blockIdx.x * 256 + threadIdx.x) * 8;
    float4 v0 = *(const float4*)(x + f);
    float4 v1 = *(const float4*)(x + f + 4);
    const double sc = s[(f >> 9) & 2047];
    f16x8 q;
    q[0] = (_Float16)fmin(fmax(rint((double)v0.x / sc), -128.0), 127.0);
    q[1] = (_Float16)fmin(fmax(rint((double)v0.y / sc), -128.0), 127.0);
    q[2] = (_Float16)fmin(fmax(rint((double)v0.z / sc), -128.0), 127.0);
    q[3] = (_Float16)fmin(fmax(rint((double)v0.w / sc), -128.0), 127.0);
    q[4] = (_Float16)fmin(fmax(rint((double)v1.x / sc), -128.0), 127.0);
    q[5] = (_Float16)fmin(fmax(rint((double)v1.y / sc), -128.0), 127.0);
    q[6] = (_Float16)fmin(fmax(rint((double)v1.z / sc), -128.0), 127.0);
    q[7] = (_Float16)fmin(fmax(rint((double)v1.w / sc), -128.0), 127.0);
    *(f16x8*)(qA + (long)z * PLANE + f) = q;
}

// ---------------------------------------------------------------------------
// Kernel 2c: one-shot Wf transpose + Dekker hi/lo split (512x512, ~1 MB).
// Output WhT/WlT col-major [n][k] f16 so final_mfma B-frags are contiguous.
// ---------------------------------------------------------------------------
__global__ __launch_bounds__(256) void wfsplit(
    const float* __restrict__ Wf, _Float16* __restrict__ WhT,
    _Float16* __restrict__ WlT)
{
    const int n0 = blockIdx.x * 64, k0 = blockIdx.y * 64;
    const int tid = threadIdx.x;
    __shared__ float T[64 * 68];
    {
        const int kr = tid >> 2, nc = (tid & 3) * 16;
#pragma unroll
        for (int j = 0; j < 4; ++j) {
            float4 v = *(const float4*)(Wf + (long)(k0 + kr) * 512 + n0 + nc + 4 * j);
            T[kr * 68 + nc + 4 * j + 0] = v.x;
            T[kr * 68 + nc + 4 * j + 1] = v.y;
            T[kr * 68 + nc + 4 * j + 2] = v.z;
            T[kr * 68 + nc + 4 * j + 3] = v.w;
        }
    }
    __syncthreads();
    const int nr = tid >> 2, kc = (tid & 3) * 16;
    f16x8 h[2], l[2];
#pragma unroll
    for (int j = 0; j < 16; ++j) {
        float wv = T[(kc + j) * 68 + nr];
        _Float16 hi = (_Float16)wv;
        h[j >> 3][j & 7] = hi;
        l[j >> 3][j & 7] = (_Float16)(wv - (float)hi);
    }
    *(f16x8*)(WhT + (long)(n0 + nr) * 512 + k0 + kc) = h[0];
    *(f16x8*)(WhT + (long)(n0 + nr) * 512 + k0 + kc + 8) = h[1];
    *(f16x8*)(WlT + (long)(n0 + nr) * 512 + k0 + kc) = l[0];
    *(f16x8*)(WlT + (long)(n0 + nr) * 512 + k0 + kc + 8) = l[1];
}

// ---------------------------------------------------------------------------
// Kernel 3: projection GEMM on the f16 MFMA pipe.  Integer operands exact
// in f16; f32 MFMA accumulation exact (<2^24) -> bit-identical to the old
// VALU path.  Epilogue = old dequant + hi/lo plane emit (V transposed).
// ---------------------------------------------------------------------------
__global__ __launch_bounds__(256) void proj_mfma(
    const _Float16* __restrict__ qA, const _Float16* __restrict__ qW,
    const double* __restrict__ saAll, const double* __restrict__ swAll,
    _Float16* __restrict__ Qh, _Float16* __restrict__ Ql,
    _Float16* __restrict__ Kh, _Float16* __restrict__ Kl,
    _Float16* __restrict__ Vh, _Float16* __restrict__ Vl,
    int b)
{
    const int z = blockIdx.z;
    const _Float16* __restrict__ A = qA + ((long)z * 4 + b) * (2048l * 512);
    const _Float16* __restrict__ Bq = qW + (long)z * 262144;
    const double* __restrict__ sa = saAll + z * 2048;
    const double* __restrict__ swz = swAll + z * 512;

    const int m0 = blockIdx.x * 64, n0 = blockIdx.y * 64;
    const int tid = threadIdx.x;
    const int w = tid >> 6, lane = tid & 63;
    const int ln = lane & 15, quad = lane >> 4;

    __shared__ __align__(16) _Float16 As[64 * 72];
    __shared__ __align__(16) _Float16 Bs[64 * 72];
    const int srow = tid >> 3, scs = (tid & 7) * 8;

    f32x4 c[4];
#pragma unroll
    for (int nt = 0; nt < 4; ++nt) { c[nt][0] = 0; c[nt][1] = 0; c[nt][2] = 0; c[nt][3] = 0; }

    f16x8 a0, a1, b0, b1;
    a0 = *(const f16x8*)(A + (long)(m0 + srow) * 512 + scs);
    a1 = *(const f16x8*)(A + (long)(m0 + 32 + srow) * 512 + scs);
    b0 = *(const f16x8*)(Bq + (long)(n0 + srow) * 512 + scs);
    b1 = *(const f16x8*)(Bq + (long)(n0 + 32 + srow) * 512 + scs);

    for (int k0 = 0; k0 < 512; k0 += 64) {
        __syncthreads();
        *(f16x8*)(As + srow * 72 + scs) = a0;
        *(f16x8*)(As + (32 + srow) * 72 + scs) = a1;
        *(f16x8*)(Bs + srow * 72 + scs) = b0;
        *(f16x8*)(Bs + (32 + srow) * 72 + scs) = b1;
        __syncthreads();
        if (k0 + 64 < 512) {
            a0 = *(const f16x8*)(A + (long)(m0 + srow) * 512 + k0 + 64 + scs);
            a1 = *(const f16x8*)(A + (long)(m0 + 32 + srow) * 512 + k0 + 64 + scs);
            b0 = *(const f16x8*)(Bq + (long)(n0 + srow) * 512 + k0 + 64 + scs);
            b1 = *(const f16x8*)(Bq + (long)(n0 + 32 + srow) * 512 + k0 + 64 + scs);
        }
#pragma unroll
        for (int ks = 0; ks < 2; ++ks) {
            f16x8 aF = *(const f16x8*)(As + (w * 16 + ln) * 72 + ks * 32 + quad * 8);
#pragma unroll
            for (int nt = 0; nt < 4; ++nt) {
                f16x8 bF = *(const f16x8*)(Bs + (nt * 16 + ln) * 72 + ks * 32 + quad * 8);
                c[nt] = MFMA16(aF, bF, c[nt]);
            }
        }
    }

#pragma unroll
    for (int nt = 0; nt < 4; ++nt)
#pragma unroll
        for (int r = 0; r < 4; ++r) {
            int t = m0 + w * 16 + quad * 4 + r;
            int n = n0 + nt * 16 + ln;
            float val = (float)((double)c[nt][r] * sa[t] * swz[n]);
            _Float16 hi = (_Float16)val;
            _Float16 lo = (_Float16)(val - (float)hi);
            int hh = n >> 6, d = n & 63;
            if (z == 2) {
                long idx = ((long)hh * 64 + d) * 2048 + t;     // transposed
                Vh[idx] = hi; Vl[idx] = lo;
            } else if (z == 1) {
                long idx = ((long)hh * 2048 + t) * 64 + d;
                Kh[idx] = hi; Kl[idx] = lo;
            } else {
                long idx = ((long)hh * 2048 + t) * 64 + d;
                Qh[idx] = hi; Ql[idx] = lo;
            }
        }
}

// ---------------------------------------------------------------------------
// Kernel 4: attention on the f16 MFMA pipe.  UNCHANGED (green R10).
// ---------------------------------------------------------------------------
__global__ __launch_bounds__(256) void attn_mfma(
    const _Float16* __restrict__ Qh0, const _Float16* __restrict__ Ql0,
    const _Float16* __restrict__ Kh0, const _Float16* __restrict__ Kl0,
    const _Float16* __restrict__ Vh0, const _Float16* __restrict__ Vl0,
    float* __restrict__ xbuf, int bbase)
{
    const int q0 = blockIdx.x * 64;
    const int h = blockIdx.y;
    const int slot = blockIdx.z;
    const int b = bbase + slot;
    const long PE = (long)8 * 2048 * 64;
    const _Float16* __restrict__ Qh = Qh0 + (long)slot * PE;
    const _Float16* __restrict__ Ql = Ql0 + (long)slot * PE;
    const _Float16* __restrict__ Kh = Kh0 + (long)slot * PE;
    const _Float16* __restrict__ Kl = Kl0 + (long)slot * PE;
    const _Float16* __restrict__ Vh = Vh0 + (long)slot * PE;
    const _Float16* __restrict__ Vl = Vl0 + (long)slot * PE;

    const int tid = threadIdx.x;
    const int w = tid >> 6, lane = tid & 63;
    const int ln = lane & 15, quad = lane >> 4;

    __shared__ __align__(16) _Float16 KsH[64 * 72];
    __shared__ __align__(16) _Float16 KsL[64 * 72];
    __shared__ __align__(16) _Float16 VsH[64 * 72];
    __shared__ __align__(16) _Float16 VsL[64 * 72];
    __shared__ __align__(16) float SP[64 * 68];
    __shared__ float mS[64], lS[64], aS[64];
    __shared__ float psums[64 * 4];

    f16x8 qh[2], ql[2];
    {
        const long r = ((long)h * 2048 + q0 + w * 16 + ln) * 64 + quad * 8;
        qh[0] = *(const f16x8*)(Qh + r);
        qh[1] = *(const f16x8*)(Qh + r + 32);
        ql[0] = *(const f16x8*)(Ql + r);
        ql[1] = *(const f16x8*)(Ql + r + 32);
    }
    if (tid < 64) { mS[tid] = -INFINITY; lS[tid] = 0.0f; }

    f32x4 O[4];
#pragma unroll
    for (int dt = 0; dt < 4; ++dt) { O[dt][0] = 0; O[dt][1] = 0; O[dt][2] = 0; O[dt][3] = 0; }

    const int srow = tid >> 3, scs = (tid & 7) * 8;
    const long kBase = (long)h * 2048;
    const long vBase = (long)h * 64;
    f16x8 sg0, sg1, sg2, sg3, sg4, sg5, sg6, sg7;
    sg0 = *(const f16x8*)(Kh + (kBase + 0 + srow) * 64 + scs);
    sg1 = *(const f16x8*)(Kh + (kBase + 0 + 32 + srow) * 64 + scs);
    sg2 = *(const f16x8*)(Kl + (kBase + 0 + srow) * 64 + scs);
    sg3 = *(const f16x8*)(Kl + (kBase + 0 + 32 + srow) * 64 + scs);
    sg4 = *(const f16x8*)(Vh + (vBase + srow) * 2048 + 0 + scs);
    sg5 = *(const f16x8*)(Vh + (vBase + 32 + srow) * 2048 + 0 + scs);
    sg6 = *(const f16x8*)(Vl + (vBase + srow) * 2048 + 0 + scs);
    sg7 = *(const f16x8*)(Vl + (vBase + 32 + srow) * 2048 + 0 + scs);

    for (int k0 = 0; k0 < 2048; k0 += 64) {
        __syncthreads();                        // B1: prior readers done
        *(f16x8*)(KsH + srow * 72 + scs)        = sg0;
        *(f16x8*)(KsH + (32 + srow) * 72 + scs) = sg1;
        *(f16x8*)(KsL + srow * 72 + scs)        = sg2;
        *(f16x8*)(KsL + (32 + srow) * 72 + scs) = sg3;
        *(f16x8*)(VsH + srow * 72 + scs)        = sg4;
        *(f16x8*)(VsH + (32 + srow) * 72 + scs) = sg5;
        *(f16x8*)(VsL + srow * 72 + scs)        = sg6;
        *(f16x8*)(VsL + (32 + srow) * 72 + scs) = sg7;
        __syncthreads();                        // B2: tiles visible
        if (k0 + 64 < 2048) {
            const int kn = k0 + 64;
            sg0 = *(const f16x8*)(Kh + (kBase + kn + srow) * 64 + scs);
            sg1 = *(const f16x8*)(Kh + (kBase + kn + 32 + srow) * 64 + scs);
            sg2 = *(const f16x8*)(Kl + (kBase + kn + srow) * 64 + scs);
            sg3 = *(const f16x8*)(Kl + (kBase + kn + 32 + srow) * 64 + scs);
            sg4 = *(const f16x8*)(Vh + (vBase + srow) * 2048 + kn + scs);
            sg5 = *(const f16x8*)(Vh + (vBase + 32 + srow) * 2048 + kn + scs);
            sg6 = *(const f16x8*)(Vl + (vBase + srow) * 2048 + kn + scs);
            sg7 = *(const f16x8*)(Vl + (vBase + 32 + srow) * 2048 + kn + scs);
        }

        // ---- S = Q K^T / 8 ----
#pragma unroll
        for (int kt = 0; kt < 4; ++kt) {
            f32x4 s; s[0] = 0; s[1] = 0; s[2] = 0; s[3] = 0;
#pragma unroll
            for (int ks = 0; ks < 2; ++ks) {
                const int off = (kt * 16 + ln) * 72 + ks * 32 + quad * 8;
                f16x8 bh = *(const f16x8*)(KsH + off);
                f16x8 bl = *(const f16x8*)(KsL + off);
                s = MFMA16(ql[ks], bh, s);
                s = MFMA16(qh[ks], bl, s);
                s = MFMA16(qh[ks], bh, s);
            }
#pragma unroll
            for (int r = 0; r < 4; ++r)
                SP[(w * 16 + quad * 4 + r) * 68 + kt * 16 + ln] = s[r] * 0.125f;
        }
        __syncthreads();                        // B3: S visible

        {
            const int row = tid >> 2, c = tid & 3;
            const float* sp = SP + row * 68 + c;
            float rm = -INFINITY;
#pragma unroll
            for (int j = 0; j < 16; ++j) rm = fmaxf(rm, sp[4 * j]);
            rm = fmaxf(rm, __shfl_xor(rm, 1));
            rm = fmaxf(rm, __shfl_xor(rm, 2));
            if (c == 0) {
                float mold = mS[row];
                float mn = fmaxf(mold, rm);
                aS[row] = __expf(mold - mn);
                mS[row] = mn;
            }
        }
        __syncthreads();                        // B4: stats visible

        {
            const int row = tid >> 2, c = tid & 3;
            const float mn = mS[row];
            float* sp = SP + row * 68 + c;
            float sum = 0.0f;
#pragma unroll
            for (int j = 0; j < 16; ++j) {
                float p = __expf(sp[4 * j] - mn);
                sum += p;
                sp[4 * j] = p * 512.0f;
            }
            psums[row * 4 + c] = sum;
        }
#pragma unroll
        for (int r = 0; r < 4; ++r) {
            const float a = aS[w * 16 + quad * 4 + r];
#pragma unroll
            for (int dt = 0; dt < 4; ++dt) O[dt][r] *= a;
        }
        __syncthreads();                        // B5: P + psums visible

        if (tid < 64)
            lS[tid] = lS[tid] * aS[tid] +
                      (psums[tid * 4 + 0] + psums[tid * 4 + 1] +
                       psums[tid * 4 + 2] + psums[tid * 4 + 3]);

        // ---- O += P V ----
#pragma unroll
        for (int ks2 = 0; ks2 < 2; ++ks2) {
            const float* pp = SP + (w * 16 + ln) * 68 + ks2 * 32 + quad * 8;
            f16x8 ph, pl;
#pragma unroll
            for (int j = 0; j < 8; ++j) {
                float p = pp[j];
                _Float16 hi = (_Float16)p;
                ph[j] = hi;
                pl[j] = (_Float16)(p - (float)hi);
            }
#pragma unroll
            for (int dt = 0; dt < 4; ++dt) {
                const int off = (dt * 16 + ln) * 72 + ks2 * 32 + quad * 8;
                f16x8 vh = *(const f16x8*)(VsH + off);
                f16x8 vl = *(const f16x8*)(VsL + off);
                O[dt] = MFMA16(pl, vh, O[dt]);
                O[dt] = MFMA16(ph, vl, O[dt]);
                O[dt] = MFMA16(ph, vh, O[dt]);
            }
        }
    }

    __syncthreads();
#pragma unroll
    for (int r = 0; r < 4; ++r) {
        const int row = w * 16 + quad * 4 + r;
        const float inv = 1.0f / (512.0f * lS[row]);
        const long base = ((long)(b * 2048 + q0 + row)) * 512 + h * 64;
#pragma unroll
        for (int dt = 0; dt < 4; ++dt)
            xbuf[base + dt * 16 + ln] = O[dt][r] * inv;
    }
}

// ---------------------------------------------------------------------------
// Kernel 5: final GEMM on the f16 MFMA pipe.  A = quantized x (int, exact
// f16); B = Wf hi/lo split, both terms chained into the same f32 accum.
// ---------------------------------------------------------------------------
__global__ __launch_bounds__(256) void final_mfma(
    const _Float16* __restrict__ qX, const _Float16* __restrict__ WhT,
    const _Float16* __restrict__ WlT, const double* __restrict__ sx,
    float* __restrict__ out)
{
    const int m0 = blockIdx.x * 64, n0 = blockIdx.y * 64;
    const int tid = threadIdx.x;
    const int w = tid >> 6, lane = tid & 63;
    const int ln = lane & 15, quad = lane >> 4;

    __shared__ __align__(16) _Float16 As[64 * 72];
    __shared__ __align__(16) _Float16 BhS[64 * 72];
    __shared__ __align__(16) _Float16 BlS[64 * 72];
    const int srow = tid >> 3, scs = (tid & 7) * 8;

    f32x4 c[4];
#pragma unroll
    for (int nt = 0; nt < 4; ++nt) { c[nt][0] = 0; c[nt][1] = 0; c[nt][2] = 0; c[nt][3] = 0; }

    f16x8 a0, a1, h0, h1, l0, l1;
    a0 = *(const f16x8*)(qX + (long)(m0 + srow) * 512 + scs);
    a1 = *(const f16x8*)(qX + (long)(m0 + 32 + srow) * 512 + scs);
    h0 = *(const f16x8*)(WhT + (long)(n0 + srow) * 512 + scs);
    h1 = *(const f16x8*)(WhT + (long)(n0 + 32 + srow) * 512 + scs);
    l0 = *(const f16x8*)(WlT + (long)(n0 + srow) * 512 + scs);
    l1 = *(const f16x8*)(WlT + (long)(n0 + 32 + srow) * 512 + scs);

    for (int k0 = 0; k0 < 512; k0 += 64) {
        __syncthreads();
        *(f16x8*)(As + srow * 72 + scs) = a0;
        *(f16x8*)(As + (32 + srow) * 72 + scs) = a1;
        *(f16x8*)(BhS + srow * 72 + scs) = h0;
        *(f16x8*)(BhS + (32 + srow) * 72 + scs) = h1;
        *(f16x8*)(BlS + srow * 72 + scs) = l0;
        *(f16x8*)(BlS + (32 + srow) * 72 + scs) = l1;
        __syncthreads();
        if (k0 + 64 < 512) {
            a0 = *(const f16x8*)(qX + (long)(m0 + srow) * 512 + k0 + 64 + scs);
            a1 = *(const f16x8*)(qX + (long)(m0 + 32 + srow) * 512 + k0 + 64 + scs);
            h0 = *(const f16x8*)(WhT + (long)(n0 + srow) * 512 + k0 + 64 + scs);
            h1 = *(const f16x8*)(WhT + (long)(n0 + 32 + srow) * 512 + k0 + 64 + scs);
            l0 = *(const f16x8*)(WlT + (long)(n0 + srow) * 512 + k0 + 64 + scs);
            l1 = *(const f16x8*)(WlT + (long)(n0 + 32 + srow) * 512 + k0 + 64 + scs);
        }
#pragma unroll
        for (int ks = 0; ks < 2; ++ks) {
            f16x8 aF = *(const f16x8*)(As + (w * 16 + ln) * 72 + ks * 32 + quad * 8);
#pragma unroll
            for (int nt = 0; nt < 4; ++nt) {
                const int off = (nt * 16 + ln) * 72 + ks * 32 + quad * 8;
                f16x8 bh = *(const f16x8*)(BhS + off);
                f16x8 bl = *(const f16x8*)(BlS + off);
                c[nt] = MFMA16(aF, bl, c[nt]);
                c[nt] = MFMA16(aF, bh, c[nt]);
            }
        }
    }

#pragma unroll
    for (int nt = 0; nt < 4; ++nt)
#pragma unroll
        for (int r = 0; r < 4; ++r) {
            int m = m0 + w * 16 + quad * 4 + r;
            int n = n0 + nt * 16 + ln;
            out[(long)m * 512 + n] = (float)((double)c[nt][r] * sx[m & 2047]);
        }
}

// ---------------------------------------------------------------------------
extern "C" void kernel_launch(void* const* d_in, const int* in_sizes, int n_in,
                              void* d_out, int out_size, void* d_ws, size_t ws_size,
                              hipStream_t stream)
{
    const float* query = (const float*)d_in[0];
    const float* key_  = (const float*)d_in[1];
    const float* value = (const float*)d_in[2];
    const float* Wq = (const float*)d_in[3];
    const float* Wk = (const float*)d_in[4];
    const float* Wv = (const float*)d_in[5];
    const float* Wf = (const float*)d_in[6];
    float* out = (float*)d_out;

    // workspace carve-up: ~70 MB
    char* p = (char*)d_ws;
    auto alloc = [&](size_t bytes) -> char* {
        char* r = p;
        p += (bytes + 255) & ~(size_t)255;
        return r;
    };
    double*   sA   = (double*)alloc(3 * 2048 * 8);
    double*   sx   = (double*)alloc(2048 * 8);
    double*   sw   = (double*)alloc(3 * 512 * 8);
    _Float16* qW   = (_Float16*)alloc((size_t)3 * 512 * 512 * 2);
    const long PE  = (long)8 * 2048 * 64;   // halfs per slot-plane
    _Float16* Qh   = (_Float16*)alloc((size_t)2 * PE * 2);
    _Float16* Ql   = (_Float16*)alloc((size_t)2 * PE * 2);
    _Float16* Kh   = (_Float16*)alloc((size_t)2 * PE * 2);
    _Float16* Kl   = (_Float16*)alloc((size_t)2 * PE * 2);
    _Float16* Vh   = (_Float16*)alloc((size_t)2 * PE * 2);
    _Float16* Vl   = (_Float16*)alloc((size_t)2 * PE * 2);
    float*    xbuf = (float*)alloc((size_t)8192 * 512 * 4);
    _Float16* qA   = (_Float16*)alloc((size_t)3 * 4 * 2048 * 512 * 2);  // also reused as qX
    _Float16* WhT  = (_Float16*)alloc((size_t)512 * 512 * 2);
    _Float16* WlT  = (_Float16*)alloc((size_t)512 * 512 * 2);

    token_scale<<<dim3(2048, 3), 256, 0, stream>>>(query, key_, value, sA);
    wquant<<<dim3(8, 3), 256, 0, stream>>>(Wq, Wk, Wv, sw, qW);
    aquant<<<dim3(2048, 3), 256, 0, stream>>>(query, key_, value, sA, qA);
    wfsplit<<<dim3(8, 8), 256, 0, stream>>>(Wf, WhT, WlT);
    for (int pair = 0; pair < 2; ++pair) {
        proj_mfma<<<dim3(32, 8, 3), 256, 0, stream>>>(qA, qW, sA, sw,
            Qh, Ql, Kh, Kl, Vh, Vl, pair * 2);
        proj_mfma<<<dim3(32, 8, 3), 256, 0, stream>>>(qA, qW, sA, sw,
            Qh + PE, Ql + PE, Kh + PE, Kl + PE, Vh + PE, Vl + PE, pair * 2 + 1);
        attn_mfma<<<dim3(32, 8, 2), 256, 0, stream>>>(Qh, Ql, Kh, Kl, Vh, Vl, xbuf, pair * 2);
    }
    token_scale<<<dim3(2048, 1), 256, 0, stream>>>(xbuf, xbuf, xbuf, sx);
    aquant<<<dim3(2048, 1), 256, 0, stream>>>(xbuf, xbuf, xbuf, sx, qA);  // qX alias
    final_mfma<<<dim3(128, 8), 256, 0, stream>>>(qA, WhT, WlT, sx, out);
}

// Round 4
// 423.635 us; speedup vs baseline: 3.4856x; 1.0424x over previous
//
#include <hip/hip_runtime.h>
#include <math.h>

// ---------------------------------------------------------------------------
// Round 13: barrier-free in-register softmax via swapped-operand QK^T.
// R12 counters: attn is top dispatch (102us x2), MfmaUtil 20%, 5 barriers +
// cross-wave LDS softmax dominate.  New structure: S^T = MFMA(K, Q) (Q's
// A-fragment registers are bit-identical to Q^T's B-fragment), so each lane
// holds 16 scores of ONE q-row -> row max/sum = in-lane + 2 shfl_xor; m,l
// in registers; P hi/lo written to a WAVE-PRIVATE LDS buffer and re-read as
// the PV B-frag (same-wave dep, no barrier); PV computes O^T = MFMA(V^T,P^T)
// with V reads at unchanged offsets.  Barriers 5 -> 2 per K-tile; SP f32
// buffer and all cross-wave phases removed; epilogue = 4 coalesced float4.
// Same 3-term Dekker products, same exp algebra (1/8 folded into exp arg:
// exp((s-m)*0.125), exact identity) -> absmax stays in the 54 class.
// Predicted: attn 102 -> ~60us, MfmaUtil ~35%, conflicts 9.4M -> ~3M,
// total 441 -> ~360us.
// ---------------------------------------------------------------------------

typedef _Float16 f16x8 __attribute__((ext_vector_type(8)));
typedef _Float16 f16x2 __attribute__((ext_vector_type(2)));
typedef float f32x4 __attribute__((ext_vector_type(4)));
#define MFMA16(a, b, c) __builtin_amdgcn_mfma_f32_16x16x32_f16((a), (b), (c), 0, 0, 0)

// ---------------------------------------------------------------------------
// Kernel 1: per-token abs-max scale (f64 decisions).  UNCHANGED (green).
// ---------------------------------------------------------------------------
__global__ __launch_bounds__(256) void token_scale(
    const float* __restrict__ x0, const float* __restrict__ x1,
    const float* __restrict__ x2, double* __restrict__ out)
{
    const int t = blockIdx.x;
    const int z = blockIdx.y;
    const float* __restrict__ x = (z == 0) ? x0 : ((z == 1) ? x1 : x2);
    const int tid = threadIdx.x;
    float m = 0.0f;
#pragma unroll
    for (int i = 0; i < 2; ++i) {
        int f = i * 256 + tid;
        int b = f >> 7, d4 = f & 127;
        float4 v = *(const float4*)(x + (long)(b * 2048 + t) * 512 + d4 * 4);
        m = fmaxf(m, fmaxf(fmaxf(fabsf(v.x), fabsf(v.y)), fmaxf(fabsf(v.z), fabsf(v.w))));
    }
#pragma unroll
    for (int off = 1; off < 64; off <<= 1) m = fmaxf(m, __shfl_xor(m, off));
    __shared__ float red[4];
    if ((tid & 63) == 0) red[tid >> 6] = m;
    __syncthreads();
    if (tid == 0) {
        m = fmaxf(fmaxf(red[0], red[1]), fmaxf(red[2], red[3]));
        out[z * 2048 + t] = fmax((double)m / 127.0, 1e-8);
    }
}

// ---------------------------------------------------------------------------
// Kernel 2: weight quantization.  UNCHANGED (green R11).
// ---------------------------------------------------------------------------
__global__ __launch_bounds__(256) void wquant(
    const float* __restrict__ Wq, const float* __restrict__ Wk,
    const float* __restrict__ Wv, double* __restrict__ sw,
    _Float16* __restrict__ qW)
{
    const int z = blockIdx.y;
    const float* __restrict__ W = (z == 0) ? Wq : (z == 1) ? Wk : Wv;
    const int col0 = blockIdx.x * 64;
    const int tid = threadIdx.x;
    const int c = tid & 63, kg = tid >> 6;

    __shared__ float redm[4][64];
    __shared__ double sS[64];
    __shared__ __align__(16) _Float16 qs[64][520];

    float m = 0.0f;
    for (int k = kg; k < 512; k += 4)
        m = fmaxf(m, fabsf(W[k * 512 + col0 + c]));
    redm[kg][c] = m;
    __syncthreads();
    if (tid < 64) {
        float mm = fmaxf(fmaxf(redm[0][tid], redm[1][tid]),
                         fmaxf(redm[2][tid], redm[3][tid]));
        double s = fmax((double)mm / 127.0, 1e-8);
        sw[z * 512 + col0 + tid] = s;
        sS[tid] = s;
    }
    __syncthreads();

    const double s = sS[c];
    for (int k = kg; k < 512; k += 4)
        qs[c][k] = (_Float16)fmin(fmax(rint((double)W[k * 512 + col0 + c] / s), -128.0), 127.0);
    __syncthreads();

    const int wc = tid >> 2, kc = (tid & 3) * 128;
    _Float16* q = qW + (long)z * 262144 + (long)(col0 + wc) * 512 + kc;
#pragma unroll
    for (int j = 0; j < 16; ++j)
        *(f16x8*)(q + j * 8) = *(const f16x8*)(&qs[wc][kc + j * 8]);
}

// ---------------------------------------------------------------------------
// Kernel 2b: activation quantization into f16 int planes.  UNCHANGED (R12).
// ---------------------------------------------------------------------------
__global__ __launch_bounds__(256) void aquant(
    const float* __restrict__ x0, const float* __restrict__ x1,
    const float* __restrict__ x2, const double* __restrict__ sAll,
    _Float16* __restrict__ qA)
{
    const int z = blockIdx.y;
    const float* __restrict__ x = (z == 0) ? x0 : ((z == 1) ? x1 : x2);
    const double* __restrict__ s = sAll + z * 2048;
    const long PLANE = (long)4 * 2048 * 512;
    const long f = ((long)blockIdx.x * 256 + threadIdx.x) * 8;
    float4 v0 = *(const float4*)(x + f);
    float4 v1 = *(const float4*)(x + f + 4);
    const double sc = s[(f >> 9) & 2047];
    f16x8 q;
    q[0] = (_Float16)fmin(fmax(rint((double)v0.x / sc), -128.0), 127.0);
    q[1] = (_Float16)fmin(fmax(rint((double)v0.y / sc), -128.0), 127.0);
    q[2] = (_Float16)fmin(fmax(rint((double)v0.z / sc), -128.0), 127.0);
    q[3] = (_Float16)fmin(fmax(rint((double)v0.w / sc), -128.0), 127.0);
    q[4] = (_Float16)fmin(fmax(rint((double)v1.x / sc), -128.0), 127.0);
    q[5] = (_Float16)fmin(fmax(rint((double)v1.y / sc), -128.0), 127.0);
    q[6] = (_Float16)fmin(fmax(rint((double)v1.z / sc), -128.0), 127.0);
    q[7] = (_Float16)fmin(fmax(rint((double)v1.w / sc), -128.0), 127.0);
    *(f16x8*)(qA + (long)z * PLANE + f) = q;
}

// ---------------------------------------------------------------------------
// Kernel 2c: one-shot Wf transpose + Dekker hi/lo split.  UNCHANGED (R12).
// ---------------------------------------------------------------------------
__global__ __launch_bounds__(256) void wfsplit(
    const float* __restrict__ Wf, _Float16* __restrict__ WhT,
    _Float16* __restrict__ WlT)
{
    const int n0 = blockIdx.x * 64, k0 = blockIdx.y * 64;
    const int tid = threadIdx.x;
    __shared__ float T[64 * 68];
    {
        const int kr = tid >> 2, nc = (tid & 3) * 16;
#pragma unroll
        for (int j = 0; j < 4; ++j) {
            float4 v = *(const float4*)(Wf + (long)(k0 + kr) * 512 + n0 + nc + 4 * j);
            T[kr * 68 + nc + 4 * j + 0] = v.x;
            T[kr * 68 + nc + 4 * j + 1] = v.y;
            T[kr * 68 + nc + 4 * j + 2] = v.z;
            T[kr * 68 + nc + 4 * j + 3] = v.w;
        }
    }
    __syncthreads();
    const int nr = tid >> 2, kc = (tid & 3) * 16;
    f16x8 h[2], l[2];
#pragma unroll
    for (int j = 0; j < 16; ++j) {
        float wv = T[(kc + j) * 68 + nr];
        _Float16 hi = (_Float16)wv;
        h[j >> 3][j & 7] = hi;
        l[j >> 3][j & 7] = (_Float16)(wv - (float)hi);
    }
    *(f16x8*)(WhT + (long)(n0 + nr) * 512 + k0 + kc) = h[0];
    *(f16x8*)(WhT + (long)(n0 + nr) * 512 + k0 + kc + 8) = h[1];
    *(f16x8*)(WlT + (long)(n0 + nr) * 512 + k0 + kc) = l[0];
    *(f16x8*)(WlT + (long)(n0 + nr) * 512 + k0 + kc + 8) = l[1];
}

// ---------------------------------------------------------------------------
// Kernel 3: projection GEMM on the f16 MFMA pipe.  UNCHANGED (green R12).
// ---------------------------------------------------------------------------
__global__ __launch_bounds__(256) void proj_mfma(
    const _Float16* __restrict__ qA, const _Float16* __restrict__ qW,
    const double* __restrict__ saAll, const double* __restrict__ swAll,
    _Float16* __restrict__ Qh, _Float16* __restrict__ Ql,
    _Float16* __restrict__ Kh, _Float16* __restrict__ Kl,
    _Float16* __restrict__ Vh, _Float16* __restrict__ Vl,
    int b)
{
    const int z = blockIdx.z;
    const _Float16* __restrict__ A = qA + ((long)z * 4 + b) * (2048l * 512);
    const _Float16* __restrict__ Bq = qW + (long)z * 262144;
    const double* __restrict__ sa = saAll + z * 2048;
    const double* __restrict__ swz = swAll + z * 512;

    const int m0 = blockIdx.x * 64, n0 = blockIdx.y * 64;
    const int tid = threadIdx.x;
    const int w = tid >> 6, lane = tid & 63;
    const int ln = lane & 15, quad = lane >> 4;

    __shared__ __align__(16) _Float16 As[64 * 72];
    __shared__ __align__(16) _Float16 Bs[64 * 72];
    const int srow = tid >> 3, scs = (tid & 7) * 8;

    f32x4 c[4];
#pragma unroll
    for (int nt = 0; nt < 4; ++nt) { c[nt][0] = 0; c[nt][1] = 0; c[nt][2] = 0; c[nt][3] = 0; }

    f16x8 a0, a1, b0, b1;
    a0 = *(const f16x8*)(A + (long)(m0 + srow) * 512 + scs);
    a1 = *(const f16x8*)(A + (long)(m0 + 32 + srow) * 512 + scs);
    b0 = *(const f16x8*)(Bq + (long)(n0 + srow) * 512 + scs);
    b1 = *(const f16x8*)(Bq + (long)(n0 + 32 + srow) * 512 + scs);

    for (int k0 = 0; k0 < 512; k0 += 64) {
        __syncthreads();
        *(f16x8*)(As + srow * 72 + scs) = a0;
        *(f16x8*)(As + (32 + srow) * 72 + scs) = a1;
        *(f16x8*)(Bs + srow * 72 + scs) = b0;
        *(f16x8*)(Bs + (32 + srow) * 72 + scs) = b1;
        __syncthreads();
        if (k0 + 64 < 512) {
            a0 = *(const f16x8*)(A + (long)(m0 + srow) * 512 + k0 + 64 + scs);
            a1 = *(const f16x8*)(A + (long)(m0 + 32 + srow) * 512 + k0 + 64 + scs);
            b0 = *(const f16x8*)(Bq + (long)(n0 + srow) * 512 + k0 + 64 + scs);
            b1 = *(const f16x8*)(Bq + (long)(n0 + 32 + srow) * 512 + k0 + 64 + scs);
        }
#pragma unroll
        for (int ks = 0; ks < 2; ++ks) {
            f16x8 aF = *(const f16x8*)(As + (w * 16 + ln) * 72 + ks * 32 + quad * 8);
#pragma unroll
            for (int nt = 0; nt < 4; ++nt) {
                f16x8 bF = *(const f16x8*)(Bs + (nt * 16 + ln) * 72 + ks * 32 + quad * 8);
                c[nt] = MFMA16(aF, bF, c[nt]);
            }
        }
    }

#pragma unroll
    for (int nt = 0; nt < 4; ++nt)
#pragma unroll
        for (int r = 0; r < 4; ++r) {
            int t = m0 + w * 16 + quad * 4 + r;
            int n = n0 + nt * 16 + ln;
            float val = (float)((double)c[nt][r] * sa[t] * swz[n]);
            _Float16 hi = (_Float16)val;
            _Float16 lo = (_Float16)(val - (float)hi);
            int hh = n >> 6, d = n & 63;
            if (z == 2) {
                long idx = ((long)hh * 64 + d) * 2048 + t;     // transposed
                Vh[idx] = hi; Vl[idx] = lo;
            } else if (z == 1) {
                long idx = ((long)hh * 2048 + t) * 64 + d;
                Kh[idx] = hi; Kl[idx] = lo;
            } else {
                long idx = ((long)hh * 2048 + t) * 64 + d;
                Qh[idx] = hi; Ql[idx] = lo;
            }
        }
}

// ---------------------------------------------------------------------------
// Kernel 4: attention, barrier-free in-register softmax (this round).
// S^T = MFMA(K, Q): lane holds 16 scores of q-row q=ln (quad-replicated
// m/l).  P hi/lo -> wave-private LDS -> PV B-frag (no barrier).  PV:
// O^T = MFMA(V^T, P^T), V offsets unchanged.  2 barriers/K-tile (staging).
// ---------------------------------------------------------------------------
__global__ __launch_bounds__(256) void attn_mfma(
    const _Float16* __restrict__ Qh0, const _Float16* __restrict__ Ql0,
    const _Float16* __restrict__ Kh0, const _Float16* __restrict__ Kl0,
    const _Float16* __restrict__ Vh0, const _Float16* __restrict__ Vl0,
    float* __restrict__ xbuf, int bbase)
{
    const int q0 = blockIdx.x * 64;
    const int h = blockIdx.y;
    const int slot = blockIdx.z;
    const int b = bbase + slot;
    const long PE = (long)8 * 2048 * 64;
    const _Float16* __restrict__ Qh = Qh0 + (long)slot * PE;
    const _Float16* __restrict__ Ql = Ql0 + (long)slot * PE;
    const _Float16* __restrict__ Kh = Kh0 + (long)slot * PE;
    const _Float16* __restrict__ Kl = Kl0 + (long)slot * PE;
    const _Float16* __restrict__ Vh = Vh0 + (long)slot * PE;
    const _Float16* __restrict__ Vl = Vl0 + (long)slot * PE;

    const int tid = threadIdx.x;
    const int w = tid >> 6, lane = tid & 63;
    const int ln = lane & 15, quad = lane >> 4;

    __shared__ __align__(16) _Float16 KsH[64 * 72];
    __shared__ __align__(16) _Float16 KsL[64 * 72];
    __shared__ __align__(16) _Float16 VsH[64 * 72];
    __shared__ __align__(16) _Float16 VsL[64 * 72];
    __shared__ __align__(16) _Float16 PTh[4][16 * 72];   // wave-private P hi
    __shared__ __align__(16) _Float16 PTl[4][16 * 72];   // wave-private P lo

    // Q fragment registers; identical content serves as B-operand of Q^T.
    f16x8 qh[2], ql[2];
    {
        const long r = ((long)h * 2048 + q0 + w * 16 + ln) * 64 + quad * 8;
        qh[0] = *(const f16x8*)(Qh + r);
        qh[1] = *(const f16x8*)(Qh + r + 32);
        ql[0] = *(const f16x8*)(Ql + r);
        ql[1] = *(const f16x8*)(Ql + r + 32);
    }

    float m_run = -INFINITY, l_run = 0.0f;   // for q = q0 + w*16 + ln

    f32x4 O[4];   // O^T[d = dt*16 + quad*4 + r][q = ln]
#pragma unroll
    for (int dt = 0; dt < 4; ++dt) { O[dt][0] = 0; O[dt][1] = 0; O[dt][2] = 0; O[dt][3] = 0; }

    const int srow = tid >> 3, scs = (tid & 7) * 8;
    const long kBase = (long)h * 2048;
    const long vBase = (long)h * 64;
    f16x8 sg0, sg1, sg2, sg3, sg4, sg5, sg6, sg7;
    sg0 = *(const f16x8*)(Kh + (kBase + 0 + srow) * 64 + scs);
    sg1 = *(const f16x8*)(Kh + (kBase + 0 + 32 + srow) * 64 + scs);
    sg2 = *(const f16x8*)(Kl + (kBase + 0 + srow) * 64 + scs);
    sg3 = *(const f16x8*)(Kl + (kBase + 0 + 32 + srow) * 64 + scs);
    sg4 = *(const f16x8*)(Vh + (vBase + srow) * 2048 + 0 + scs);
    sg5 = *(const f16x8*)(Vh + (vBase + 32 + srow) * 2048 + 0 + scs);
    sg6 = *(const f16x8*)(Vl + (vBase + srow) * 2048 + 0 + scs);
    sg7 = *(const f16x8*)(Vl + (vBase + 32 + srow) * 2048 + 0 + scs);

    for (int k0 = 0; k0 < 2048; k0 += 64) {
        __syncthreads();                        // B1: prior readers done
        *(f16x8*)(KsH + srow * 72 + scs)        = sg0;
        *(f16x8*)(KsH + (32 + srow) * 72 + scs) = sg1;
        *(f16x8*)(KsL + srow * 72 + scs)        = sg2;
        *(f16x8*)(KsL + (32 + srow) * 72 + scs) = sg3;
        *(f16x8*)(VsH + srow * 72 + scs)        = sg4;
        *(f16x8*)(VsH + (32 + srow) * 72 + scs) = sg5;
        *(f16x8*)(VsL + srow * 72 + scs)        = sg6;
        *(f16x8*)(VsL + (32 + srow) * 72 + scs) = sg7;
        __syncthreads();                        // B2: tiles visible
        if (k0 + 64 < 2048) {
            const int kn = k0 + 64;
            sg0 = *(const f16x8*)(Kh + (kBase + kn + srow) * 64 + scs);
            sg1 = *(const f16x8*)(Kh + (kBase + kn + 32 + srow) * 64 + scs);
            sg2 = *(const f16x8*)(Kl + (kBase + kn + srow) * 64 + scs);
            sg3 = *(const f16x8*)(Kl + (kBase + kn + 32 + srow) * 64 + scs);
            sg4 = *(const f16x8*)(Vh + (vBase + srow) * 2048 + kn + scs);
            sg5 = *(const f16x8*)(Vh + (vBase + 32 + srow) * 2048 + kn + scs);
            sg6 = *(const f16x8*)(Vl + (vBase + srow) * 2048 + kn + scs);
            sg7 = *(const f16x8*)(Vl + (vBase + 32 + srow) * 2048 + kn + scs);
        }

        // ---- S^T = K Q^T (4 key-subtiles x 2 k-steps x 3 Dekker terms) ----
        // D layout: lane holds S^T[key = kt*16 + quad*4 + r][q = ln].
        f32x4 sT[4];
#pragma unroll
        for (int kt = 0; kt < 4; ++kt) {
            f32x4 s; s[0] = 0; s[1] = 0; s[2] = 0; s[3] = 0;
#pragma unroll
            for (int ks = 0; ks < 2; ++ks) {
                const int off = (kt * 16 + ln) * 72 + ks * 32 + quad * 8;
                f16x8 kh = *(const f16x8*)(KsH + off);
                f16x8 kl = *(const f16x8*)(KsL + off);
                s = MFMA16(kl, qh[ks], s);
                s = MFMA16(kh, ql[ks], s);
                s = MFMA16(kh, qh[ks], s);
            }
            sT[kt] = s;
        }

        // ---- in-register online softmax for q = ln (quad-replicated) ----
        float rm = -INFINITY;
#pragma unroll
        for (int kt = 0; kt < 4; ++kt)
#pragma unroll
            for (int r = 0; r < 4; ++r) rm = fmaxf(rm, sT[kt][r]);
        rm = fmaxf(rm, __shfl_xor(rm, 16));
        rm = fmaxf(rm, __shfl_xor(rm, 32));
        const float mn = fmaxf(m_run, rm);
        const float a = __expf((m_run - mn) * 0.125f);   // 1/sqrt(dk)=1/8 folded in
        m_run = mn;

        float sum = 0.0f;
#pragma unroll
        for (int kt = 0; kt < 4; ++kt) {
#pragma unroll
            for (int r = 0; r < 4; r += 2) {
                float p0 = __expf((sT[kt][r]     - mn) * 0.125f);
                float p1 = __expf((sT[kt][r + 1] - mn) * 0.125f);
                sum += p0 + p1;
                float s0 = p0 * 512.0f, s1 = p1 * 512.0f;   // exact pow2 pre-scale
                _Float16 h0 = (_Float16)s0, h1 = (_Float16)s1;
                f16x2 hp = {h0, h1};
                f16x2 lp = {(_Float16)(s0 - (float)h0), (_Float16)(s1 - (float)h1)};
                const int poff = ln * 72 + kt * 16 + quad * 4 + r;
                *(f16x2*)(&PTh[w][poff]) = hp;
                *(f16x2*)(&PTl[w][poff]) = lp;
            }
        }
        sum += __shfl_xor(sum, 16);
        sum += __shfl_xor(sum, 32);
        l_run = l_run * a + sum;

#pragma unroll
        for (int dt = 0; dt < 4; ++dt) {
            O[dt][0] *= a; O[dt][1] *= a; O[dt][2] *= a; O[dt][3] *= a;
        }

        // ---- O^T += V^T P^T (wave-private PT: NO barrier needed) ----
#pragma unroll
        for (int ks2 = 0; ks2 < 2; ++ks2) {
            f16x8 ph = *(const f16x8*)(&PTh[w][ln * 72 + ks2 * 32 + quad * 8]);
            f16x8 pl = *(const f16x8*)(&PTl[w][ln * 72 + ks2 * 32 + quad * 8]);
#pragma unroll
            for (int dt = 0; dt < 4; ++dt) {
                const int off = (dt * 16 + ln) * 72 + ks2 * 32 + quad * 8;
                f16x8 vh = *(const f16x8*)(VsH + off);
                f16x8 vl = *(const f16x8*)(VsL + off);
                O[dt] = MFMA16(vh, pl, O[dt]);
                O[dt] = MFMA16(vl, ph, O[dt]);
                O[dt] = MFMA16(vh, ph, O[dt]);
            }
        }
    }

    // ---- epilogue: O^T[d][q=ln] -> xbuf rows, 4 coalesced float4/lane ----
    const float inv = 1.0f / (512.0f * l_run);
    const long base = ((long)(b * 2048 + q0 + w * 16 + ln)) * 512 + h * 64 + quad * 4;
#pragma unroll
    for (int dt = 0; dt < 4; ++dt) {
        float4 o;
        o.x = O[dt][0] * inv; o.y = O[dt][1] * inv;
        o.z = O[dt][2] * inv; o.w = O[dt][3] * inv;
        *(float4*)(xbuf + base + dt * 16) = o;
    }
}

// ---------------------------------------------------------------------------
// Kernel 5: final GEMM on the f16 MFMA pipe.  UNCHANGED (green R12).
// ---------------------------------------------------------------------------
__global__ __launch_bounds__(256) void final_mfma(
    const _Float16* __restrict__ qX, const _Float16* __restrict__ WhT,
    const _Float16* __restrict__ WlT, const double* __restrict__ sx,
    float* __restrict__ out)
{
    const int m0 = blockIdx.x * 64, n0 = blockIdx.y * 64;
    const int tid = threadIdx.x;
    const int w = tid >> 6, lane = tid & 63;
    const int ln = lane & 15, quad = lane >> 4;

    __shared__ __align__(16) _Float16 As[64 * 72];
    __shared__ __align__(16) _Float16 BhS[64 * 72];
    __shared__ __align__(16) _Float16 BlS[64 * 72];
    const int srow = tid >> 3, scs = (tid & 7) * 8;

    f32x4 c[4];
#pragma unroll
    for (int nt = 0; nt < 4; ++nt) { c[nt][0] = 0; c[nt][1] = 0; c[nt][2] = 0; c[nt][3] = 0; }

    f16x8 a0, a1, h0, h1, l0, l1;
    a0 = *(const f16x8*)(qX + (long)(m0 + srow) * 512 + scs);
    a1 = *(const f16x8*)(qX + (long)(m0 + 32 + srow) * 512 + scs);
    h0 = *(const f16x8*)(WhT + (long)(n0 + srow) * 512 + scs);
    h1 = *(const f16x8*)(WhT + (long)(n0 + 32 + srow) * 512 + scs);
    l0 = *(const f16x8*)(WlT + (long)(n0 + srow) * 512 + scs);
    l1 = *(const f16x8*)(WlT + (long)(n0 + 32 + srow) * 512 + scs);

    for (int k0 = 0; k0 < 512; k0 += 64) {
        __syncthreads();
        *(f16x8*)(As + srow * 72 + scs) = a0;
        *(f16x8*)(As + (32 + srow) * 72 + scs) = a1;
        *(f16x8*)(BhS + srow * 72 + scs) = h0;
        *(f16x8*)(BhS + (32 + srow) * 72 + scs) = h1;
        *(f16x8*)(BlS + srow * 72 + scs) = l0;
        *(f16x8*)(BlS + (32 + srow) * 72 + scs) = l1;
        __syncthreads();
        if (k0 + 64 < 512) {
            a0 = *(const f16x8*)(qX + (long)(m0 + srow) * 512 + k0 + 64 + scs);
            a1 = *(const f16x8*)(qX + (long)(m0 + 32 + srow) * 512 + k0 + 64 + scs);
            h0 = *(const f16x8*)(WhT + (long)(n0 + srow) * 512 + k0 + 64 + scs);
            h1 = *(const f16x8*)(WhT + (long)(n0 + 32 + srow) * 512 + k0 + 64 + scs);
            l0 = *(const f16x8*)(WlT + (long)(n0 + srow) * 512 + k0 + 64 + scs);
            l1 = *(const f16x8*)(WlT + (long)(n0 + 32 + srow) * 512 + k0 + 64 + scs);
        }
#pragma unroll
        for (int ks = 0; ks < 2; ++ks) {
            f16x8 aF = *(const f16x8*)(As + (w * 16 + ln) * 72 + ks * 32 + quad * 8);
#pragma unroll
            for (int nt = 0; nt < 4; ++nt) {
                const int off = (nt * 16 + ln) * 72 + ks * 32 + quad * 8;
                f16x8 bh = *(const f16x8*)(BhS + off);
                f16x8 bl = *(const f16x8*)(BlS + off);
                c[nt] = MFMA16(aF, bl, c[nt]);
                c[nt] = MFMA16(aF, bh, c[nt]);
            }
        }
    }

#pragma unroll
    for (int nt = 0; nt < 4; ++nt)
#pragma unroll
        for (int r = 0; r < 4; ++r) {
            int m = m0 + w * 16 + quad * 4 + r;
            int n = n0 + nt * 16 + ln;
            out[(long)m * 512 + n] = (float)((double)c[nt][r] * sx[m & 2047]);
        }
}

// ---------------------------------------------------------------------------
extern "C" void kernel_launch(void* const* d_in, const int* in_sizes, int n_in,
                              void* d_out, int out_size, void* d_ws, size_t ws_size,
                              hipStream_t stream)
{
    const float* query = (const float*)d_in[0];
    const float* key_  = (const float*)d_in[1];
    const float* value = (const float*)d_in[2];
    const float* Wq = (const float*)d_in[3];
    const float* Wk = (const float*)d_in[4];
    const float* Wv = (const float*)d_in[5];
    const float* Wf = (const float*)d_in[6];
    float* out = (float*)d_out;

    // workspace carve-up: ~70 MB
    char* p = (char*)d_ws;
    auto alloc = [&](size_t bytes) -> char* {
        char* r = p;
        p += (bytes + 255) & ~(size_t)255;
        return r;
    };
    double*   sA   = (double*)alloc(3 * 2048 * 8);
    double*   sx   = (double*)alloc(2048 * 8);
    double*   sw   = (double*)alloc(3 * 512 * 8);
    _Float16* qW   = (_Float16*)alloc((size_t)3 * 512 * 512 * 2);
    const long PE  = (long)8 * 2048 * 64;   // halfs per slot-plane
    _Float16* Qh   = (_Float16*)alloc((size_t)2 * PE * 2);
    _Float16* Ql   = (_Float16*)alloc((size_t)2 * PE * 2);
    _Float16* Kh   = (_Float16*)alloc((size_t)2 * PE * 2);
    _Float16* Kl   = (_Float16*)alloc((size_t)2 * PE * 2);
    _Float16* Vh   = (_Float16*)alloc((size_t)2 * PE * 2);
    _Float16* Vl   = (_Float16*)alloc((size_t)2 * PE * 2);
    float*    xbuf = (float*)alloc((size_t)8192 * 512 * 4);
    _Float16* qA   = (_Float16*)alloc((size_t)3 * 4 * 2048 * 512 * 2);  // also reused as qX
    _Float16* WhT  = (_Float16*)alloc((size_t)512 * 512 * 2);
    _Float16* WlT  = (_Float16*)alloc((size_t)512 * 512 * 2);

    token_scale<<<dim3(2048, 3), 256, 0, stream>>>(query, key_, value, sA);
    wquant<<<dim3(8, 3), 256, 0, stream>>>(Wq, Wk, Wv, sw, qW);
    aquant<<<dim3(2048, 3), 256, 0, stream>>>(query, key_, value, sA, qA);
    wfsplit<<<dim3(8, 8), 256, 0, stream>>>(Wf, WhT, WlT);
    for (int pair = 0; pair < 2; ++pair) {
        proj_mfma<<<dim3(32, 8, 3), 256, 0, stream>>>(qA, qW, sA, sw,
            Qh, Ql, Kh, Kl, Vh, Vl, pair * 2);
        proj_mfma<<<dim3(32, 8, 3), 256, 0, stream>>>(qA, qW, sA, sw,
            Qh + PE, Ql + PE, Kh + PE, Kl + PE, Vh + PE, Vl + PE, pair * 2 + 1);
        attn_mfma<<<dim3(32, 8, 2), 256, 0, stream>>>(Qh, Ql, Kh, Kl, Vh, Vl, xbuf, pair * 2);
    }
    token_scale<<<dim3(2048, 1), 256, 0, stream>>>(xbuf, xbuf, xbuf, sx);
    aquant<<<dim3(2048, 1), 256, 0, stream>>>(xbuf, xbuf, xbuf, sx, qA);  // qX alias
    final_mfma<<<dim3(128, 8), 256, 0, stream>>>(qA, WhT, WlT, sx, out);
}

// Round 5
// 416.691 us; speedup vs baseline: 3.5437x; 1.0167x over previous
//
#include <hip/hip_runtime.h>
#include <math.h>

// ---------------------------------------------------------------------------
// Round 14: XCD-aware swizzle for attention (+ setprio on MFMA clusters).
// R13 counters: attn FETCH_SIZE 68 MB vs ~24 MB compulsory (3x over-fetch),
// hbm 850 GB/s -> fetch time ~= runtime: attn is staged-fetch bound.  Cause:
// consecutive q-tile blocks (sharing a K/V panel) round-robin across XCDs,
// so every XCD L2 juggles all 16 (h,slot) K/V sets (16 MB >> 4 MB).  Remap
// (bijective): XCD x owns head x, both slots -> 3 MB working set per XCD L2.
// wg = x+32y+256z; xcd=wg&7; j=wg>>3; pair=2*xcd+(j>>5); qtile=j&31.
// Index remap only + s_setprio scheduling hint -> numerics bit-identical.
// Predicted: attn FETCH 68 -> ~30 MB, dur 94 -> ~55-70 us, total ~360 us.
// ---------------------------------------------------------------------------

typedef _Float16 f16x8 __attribute__((ext_vector_type(8)));
typedef _Float16 f16x2 __attribute__((ext_vector_type(2)));
typedef float f32x4 __attribute__((ext_vector_type(4)));
#define MFMA16(a, b, c) __builtin_amdgcn_mfma_f32_16x16x32_f16((a), (b), (c), 0, 0, 0)

// ---------------------------------------------------------------------------
// Kernel 1: per-token abs-max scale (f64 decisions).  UNCHANGED (green).
// ---------------------------------------------------------------------------
__global__ __launch_bounds__(256) void token_scale(
    const float* __restrict__ x0, const float* __restrict__ x1,
    const float* __restrict__ x2, double* __restrict__ out)
{
    const int t = blockIdx.x;
    const int z = blockIdx.y;
    const float* __restrict__ x = (z == 0) ? x0 : ((z == 1) ? x1 : x2);
    const int tid = threadIdx.x;
    float m = 0.0f;
#pragma unroll
    for (int i = 0; i < 2; ++i) {
        int f = i * 256 + tid;
        int b = f >> 7, d4 = f & 127;
        float4 v = *(const float4*)(x + (long)(b * 2048 + t) * 512 + d4 * 4);
        m = fmaxf(m, fmaxf(fmaxf(fabsf(v.x), fabsf(v.y)), fmaxf(fabsf(v.z), fabsf(v.w))));
    }
#pragma unroll
    for (int off = 1; off < 64; off <<= 1) m = fmaxf(m, __shfl_xor(m, off));
    __shared__ float red[4];
    if ((tid & 63) == 0) red[tid >> 6] = m;
    __syncthreads();
    if (tid == 0) {
        m = fmaxf(fmaxf(red[0], red[1]), fmaxf(red[2], red[3]));
        out[z * 2048 + t] = fmax((double)m / 127.0, 1e-8);
    }
}

// ---------------------------------------------------------------------------
// Kernel 2: weight quantization.  UNCHANGED (green R11).
// ---------------------------------------------------------------------------
__global__ __launch_bounds__(256) void wquant(
    const float* __restrict__ Wq, const float* __restrict__ Wk,
    const float* __restrict__ Wv, double* __restrict__ sw,
    _Float16* __restrict__ qW)
{
    const int z = blockIdx.y;
    const float* __restrict__ W = (z == 0) ? Wq : (z == 1) ? Wk : Wv;
    const int col0 = blockIdx.x * 64;
    const int tid = threadIdx.x;
    const int c = tid & 63, kg = tid >> 6;

    __shared__ float redm[4][64];
    __shared__ double sS[64];
    __shared__ __align__(16) _Float16 qs[64][520];

    float m = 0.0f;
    for (int k = kg; k < 512; k += 4)
        m = fmaxf(m, fabsf(W[k * 512 + col0 + c]));
    redm[kg][c] = m;
    __syncthreads();
    if (tid < 64) {
        float mm = fmaxf(fmaxf(redm[0][tid], redm[1][tid]),
                         fmaxf(redm[2][tid], redm[3][tid]));
        double s = fmax((double)mm / 127.0, 1e-8);
        sw[z * 512 + col0 + tid] = s;
        sS[tid] = s;
    }
    __syncthreads();

    const double s = sS[c];
    for (int k = kg; k < 512; k += 4)
        qs[c][k] = (_Float16)fmin(fmax(rint((double)W[k * 512 + col0 + c] / s), -128.0), 127.0);
    __syncthreads();

    const int wc = tid >> 2, kc = (tid & 3) * 128;
    _Float16* q = qW + (long)z * 262144 + (long)(col0 + wc) * 512 + kc;
#pragma unroll
    for (int j = 0; j < 16; ++j)
        *(f16x8*)(q + j * 8) = *(const f16x8*)(&qs[wc][kc + j * 8]);
}

// ---------------------------------------------------------------------------
// Kernel 2b: activation quantization into f16 int planes.  UNCHANGED (R12).
// ---------------------------------------------------------------------------
__global__ __launch_bounds__(256) void aquant(
    const float* __restrict__ x0, const float* __restrict__ x1,
    const float* __restrict__ x2, const double* __restrict__ sAll,
    _Float16* __restrict__ qA)
{
    const int z = blockIdx.y;
    const float* __restrict__ x = (z == 0) ? x0 : ((z == 1) ? x1 : x2);
    const double* __restrict__ s = sAll + z * 2048;
    const long PLANE = (long)4 * 2048 * 512;
    const long f = ((long)blockIdx.x * 256 + threadIdx.x) * 8;
    float4 v0 = *(const float4*)(x + f);
    float4 v1 = *(const float4*)(x + f + 4);
    const double sc = s[(f >> 9) & 2047];
    f16x8 q;
    q[0] = (_Float16)fmin(fmax(rint((double)v0.x / sc), -128.0), 127.0);
    q[1] = (_Float16)fmin(fmax(rint((double)v0.y / sc), -128.0), 127.0);
    q[2] = (_Float16)fmin(fmax(rint((double)v0.z / sc), -128.0), 127.0);
    q[3] = (_Float16)fmin(fmax(rint((double)v0.w / sc), -128.0), 127.0);
    q[4] = (_Float16)fmin(fmax(rint((double)v1.x / sc), -128.0), 127.0);
    q[5] = (_Float16)fmin(fmax(rint((double)v1.y / sc), -128.0), 127.0);
    q[6] = (_Float16)fmin(fmax(rint((double)v1.z / sc), -128.0), 127.0);
    q[7] = (_Float16)fmin(fmax(rint((double)v1.w / sc), -128.0), 127.0);
    *(f16x8*)(qA + (long)z * PLANE + f) = q;
}

// ---------------------------------------------------------------------------
// Kernel 2c: one-shot Wf transpose + Dekker hi/lo split.  UNCHANGED (R12).
// ---------------------------------------------------------------------------
__global__ __launch_bounds__(256) void wfsplit(
    const float* __restrict__ Wf, _Float16* __restrict__ WhT,
    _Float16* __restrict__ WlT)
{
    const int n0 = blockIdx.x * 64, k0 = blockIdx.y * 64;
    const int tid = threadIdx.x;
    __shared__ float T[64 * 68];
    {
        const int kr = tid >> 2, nc = (tid & 3) * 16;
#pragma unroll
        for (int j = 0; j < 4; ++j) {
            float4 v = *(const float4*)(Wf + (long)(k0 + kr) * 512 + n0 + nc + 4 * j);
            T[kr * 68 + nc + 4 * j + 0] = v.x;
            T[kr * 68 + nc + 4 * j + 1] = v.y;
            T[kr * 68 + nc + 4 * j + 2] = v.z;
            T[kr * 68 + nc + 4 * j + 3] = v.w;
        }
    }
    __syncthreads();
    const int nr = tid >> 2, kc = (tid & 3) * 16;
    f16x8 h[2], l[2];
#pragma unroll
    for (int j = 0; j < 16; ++j) {
        float wv = T[(kc + j) * 68 + nr];
        _Float16 hi = (_Float16)wv;
        h[j >> 3][j & 7] = hi;
        l[j >> 3][j & 7] = (_Float16)(wv - (float)hi);
    }
    *(f16x8*)(WhT + (long)(n0 + nr) * 512 + k0 + kc) = h[0];
    *(f16x8*)(WhT + (long)(n0 + nr) * 512 + k0 + kc + 8) = h[1];
    *(f16x8*)(WlT + (long)(n0 + nr) * 512 + k0 + kc) = l[0];
    *(f16x8*)(WlT + (long)(n0 + nr) * 512 + k0 + kc + 8) = l[1];
}

// ---------------------------------------------------------------------------
// Kernel 3: projection GEMM on the f16 MFMA pipe.  UNCHANGED (green R12).
// ---------------------------------------------------------------------------
__global__ __launch_bounds__(256) void proj_mfma(
    const _Float16* __restrict__ qA, const _Float16* __restrict__ qW,
    const double* __restrict__ saAll, const double* __restrict__ swAll,
    _Float16* __restrict__ Qh, _Float16* __restrict__ Ql,
    _Float16* __restrict__ Kh, _Float16* __restrict__ Kl,
    _Float16* __restrict__ Vh, _Float16* __restrict__ Vl,
    int b)
{
    const int z = blockIdx.z;
    const _Float16* __restrict__ A = qA + ((long)z * 4 + b) * (2048l * 512);
    const _Float16* __restrict__ Bq = qW + (long)z * 262144;
    const double* __restrict__ sa = saAll + z * 2048;
    const double* __restrict__ swz = swAll + z * 512;

    const int m0 = blockIdx.x * 64, n0 = blockIdx.y * 64;
    const int tid = threadIdx.x;
    const int w = tid >> 6, lane = tid & 63;
    const int ln = lane & 15, quad = lane >> 4;

    __shared__ __align__(16) _Float16 As[64 * 72];
    __shared__ __align__(16) _Float16 Bs[64 * 72];
    const int srow = tid >> 3, scs = (tid & 7) * 8;

    f32x4 c[4];
#pragma unroll
    for (int nt = 0; nt < 4; ++nt) { c[nt][0] = 0; c[nt][1] = 0; c[nt][2] = 0; c[nt][3] = 0; }

    f16x8 a0, a1, b0, b1;
    a0 = *(const f16x8*)(A + (long)(m0 + srow) * 512 + scs);
    a1 = *(const f16x8*)(A + (long)(m0 + 32 + srow) * 512 + scs);
    b0 = *(const f16x8*)(Bq + (long)(n0 + srow) * 512 + scs);
    b1 = *(const f16x8*)(Bq + (long)(n0 + 32 + srow) * 512 + scs);

    for (int k0 = 0; k0 < 512; k0 += 64) {
        __syncthreads();
        *(f16x8*)(As + srow * 72 + scs) = a0;
        *(f16x8*)(As + (32 + srow) * 72 + scs) = a1;
        *(f16x8*)(Bs + srow * 72 + scs) = b0;
        *(f16x8*)(Bs + (32 + srow) * 72 + scs) = b1;
        __syncthreads();
        if (k0 + 64 < 512) {
            a0 = *(const f16x8*)(A + (long)(m0 + srow) * 512 + k0 + 64 + scs);
            a1 = *(const f16x8*)(A + (long)(m0 + 32 + srow) * 512 + k0 + 64 + scs);
            b0 = *(const f16x8*)(Bq + (long)(n0 + srow) * 512 + k0 + 64 + scs);
            b1 = *(const f16x8*)(Bq + (long)(n0 + 32 + srow) * 512 + k0 + 64 + scs);
        }
#pragma unroll
        for (int ks = 0; ks < 2; ++ks) {
            f16x8 aF = *(const f16x8*)(As + (w * 16 + ln) * 72 + ks * 32 + quad * 8);
#pragma unroll
            for (int nt = 0; nt < 4; ++nt) {
                f16x8 bF = *(const f16x8*)(Bs + (nt * 16 + ln) * 72 + ks * 32 + quad * 8);
                c[nt] = MFMA16(aF, bF, c[nt]);
            }
        }
    }

#pragma unroll
    for (int nt = 0; nt < 4; ++nt)
#pragma unroll
        for (int r = 0; r < 4; ++r) {
            int t = m0 + w * 16 + quad * 4 + r;
            int n = n0 + nt * 16 + ln;
            float val = (float)((double)c[nt][r] * sa[t] * swz[n]);
            _Float16 hi = (_Float16)val;
            _Float16 lo = (_Float16)(val - (float)hi);
            int hh = n >> 6, d = n & 63;
            if (z == 2) {
                long idx = ((long)hh * 64 + d) * 2048 + t;     // transposed
                Vh[idx] = hi; Vl[idx] = lo;
            } else if (z == 1) {
                long idx = ((long)hh * 2048 + t) * 64 + d;
                Kh[idx] = hi; Kl[idx] = lo;
            } else {
                long idx = ((long)hh * 2048 + t) * 64 + d;
                Qh[idx] = hi; Ql[idx] = lo;
            }
        }
}

// ---------------------------------------------------------------------------
// Kernel 4: attention.  This round: XCD-aware block swizzle (head->XCD) so
// each XCD's L2 holds one head's K/V (3 MB <= 4 MB); setprio around MFMA
// clusters.  All arithmetic identical to green R13.
// ---------------------------------------------------------------------------
__global__ __launch_bounds__(256) void attn_mfma(
    const _Float16* __restrict__ Qh0, const _Float16* __restrict__ Ql0,
    const _Float16* __restrict__ Kh0, const _Float16* __restrict__ Kl0,
    const _Float16* __restrict__ Vh0, const _Float16* __restrict__ Vl0,
    float* __restrict__ xbuf, int bbase)
{
    // ---- XCD-aware bijective remap (index-only; numerics untouched) ----
    // wg linear id -> xcd = wg&7 (HW round-robin); XCD x owns head x.
    const int wg = blockIdx.x + (blockIdx.y << 5) + (blockIdx.z << 8);
    const int xcd = wg & 7, j = wg >> 3;
    const int pair = (xcd << 1) + (j >> 5);     // 0..15 = h*2 + slot
    const int q0 = (j & 31) * 64;
    const int h = pair >> 1;
    const int slot = pair & 1;
    const int b = bbase + slot;

    const long PE = (long)8 * 2048 * 64;
    const _Float16* __restrict__ Qh = Qh0 + (long)slot * PE;
    const _Float16* __restrict__ Ql = Ql0 + (long)slot * PE;
    const _Float16* __restrict__ Kh = Kh0 + (long)slot * PE;
    const _Float16* __restrict__ Kl = Kl0 + (long)slot * PE;
    const _Float16* __restrict__ Vh = Vh0 + (long)slot * PE;
    const _Float16* __restrict__ Vl = Vl0 + (long)slot * PE;

    const int tid = threadIdx.x;
    const int w = tid >> 6, lane = tid & 63;
    const int ln = lane & 15, quad = lane >> 4;

    __shared__ __align__(16) _Float16 KsH[64 * 72];
    __shared__ __align__(16) _Float16 KsL[64 * 72];
    __shared__ __align__(16) _Float16 VsH[64 * 72];
    __shared__ __align__(16) _Float16 VsL[64 * 72];
    __shared__ __align__(16) _Float16 PTh[4][16 * 72];   // wave-private P hi
    __shared__ __align__(16) _Float16 PTl[4][16 * 72];   // wave-private P lo

    // Q fragment registers; identical content serves as B-operand of Q^T.
    f16x8 qh[2], ql[2];
    {
        const long r = ((long)h * 2048 + q0 + w * 16 + ln) * 64 + quad * 8;
        qh[0] = *(const f16x8*)(Qh + r);
        qh[1] = *(const f16x8*)(Qh + r + 32);
        ql[0] = *(const f16x8*)(Ql + r);
        ql[1] = *(const f16x8*)(Ql + r + 32);
    }

    float m_run = -INFINITY, l_run = 0.0f;   // for q = q0 + w*16 + ln

    f32x4 O[4];   // O^T[d = dt*16 + quad*4 + r][q = ln]
#pragma unroll
    for (int dt = 0; dt < 4; ++dt) { O[dt][0] = 0; O[dt][1] = 0; O[dt][2] = 0; O[dt][3] = 0; }

    const int srow = tid >> 3, scs = (tid & 7) * 8;
    const long kBase = (long)h * 2048;
    const long vBase = (long)h * 64;
    f16x8 sg0, sg1, sg2, sg3, sg4, sg5, sg6, sg7;
    sg0 = *(const f16x8*)(Kh + (kBase + 0 + srow) * 64 + scs);
    sg1 = *(const f16x8*)(Kh + (kBase + 0 + 32 + srow) * 64 + scs);
    sg2 = *(const f16x8*)(Kl + (kBase + 0 + srow) * 64 + scs);
    sg3 = *(const f16x8*)(Kl + (kBase + 0 + 32 + srow) * 64 + scs);
    sg4 = *(const f16x8*)(Vh + (vBase + srow) * 2048 + 0 + scs);
    sg5 = *(const f16x8*)(Vh + (vBase + 32 + srow) * 2048 + 0 + scs);
    sg6 = *(const f16x8*)(Vl + (vBase + srow) * 2048 + 0 + scs);
    sg7 = *(const f16x8*)(Vl + (vBase + 32 + srow) * 2048 + 0 + scs);

    for (int k0 = 0; k0 < 2048; k0 += 64) {
        __syncthreads();                        // B1: prior readers done
        *(f16x8*)(KsH + srow * 72 + scs)        = sg0;
        *(f16x8*)(KsH + (32 + srow) * 72 + scs) = sg1;
        *(f16x8*)(KsL + srow * 72 + scs)        = sg2;
        *(f16x8*)(KsL + (32 + srow) * 72 + scs) = sg3;
        *(f16x8*)(VsH + srow * 72 + scs)        = sg4;
        *(f16x8*)(VsH + (32 + srow) * 72 + scs) = sg5;
        *(f16x8*)(VsL + srow * 72 + scs)        = sg6;
        *(f16x8*)(VsL + (32 + srow) * 72 + scs) = sg7;
        __syncthreads();                        // B2: tiles visible
        if (k0 + 64 < 2048) {
            const int kn = k0 + 64;
            sg0 = *(const f16x8*)(Kh + (kBase + kn + srow) * 64 + scs);
            sg1 = *(const f16x8*)(Kh + (kBase + kn + 32 + srow) * 64 + scs);
            sg2 = *(const f16x8*)(Kl + (kBase + kn + srow) * 64 + scs);
            sg3 = *(const f16x8*)(Kl + (kBase + kn + 32 + srow) * 64 + scs);
            sg4 = *(const f16x8*)(Vh + (vBase + srow) * 2048 + kn + scs);
            sg5 = *(const f16x8*)(Vh + (vBase + 32 + srow) * 2048 + kn + scs);
            sg6 = *(const f16x8*)(Vl + (vBase + srow) * 2048 + kn + scs);
            sg7 = *(const f16x8*)(Vl + (vBase + 32 + srow) * 2048 + kn + scs);
        }

        // ---- S^T = K Q^T (4 key-subtiles x 2 k-steps x 3 Dekker terms) ----
        f32x4 sT[4];
        __builtin_amdgcn_s_setprio(1);
#pragma unroll
        for (int kt = 0; kt < 4; ++kt) {
            f32x4 s; s[0] = 0; s[1] = 0; s[2] = 0; s[3] = 0;
#pragma unroll
            for (int ks = 0; ks < 2; ++ks) {
                const int off = (kt * 16 + ln) * 72 + ks * 32 + quad * 8;
                f16x8 kh = *(const f16x8*)(KsH + off);
                f16x8 kl = *(const f16x8*)(KsL + off);
                s = MFMA16(kl, qh[ks], s);
                s = MFMA16(kh, ql[ks], s);
                s = MFMA16(kh, qh[ks], s);
            }
            sT[kt] = s;
        }
        __builtin_amdgcn_s_setprio(0);

        // ---- in-register online softmax for q = ln (quad-replicated) ----
        float rm = -INFINITY;
#pragma unroll
        for (int kt = 0; kt < 4; ++kt)
#pragma unroll
            for (int r = 0; r < 4; ++r) rm = fmaxf(rm, sT[kt][r]);
        rm = fmaxf(rm, __shfl_xor(rm, 16));
        rm = fmaxf(rm, __shfl_xor(rm, 32));
        const float mn = fmaxf(m_run, rm);
        const float a = __expf((m_run - mn) * 0.125f);   // 1/sqrt(dk)=1/8 folded in
        m_run = mn;

        float sum = 0.0f;
#pragma unroll
        for (int kt = 0; kt < 4; ++kt) {
#pragma unroll
            for (int r = 0; r < 4; r += 2) {
                float p0 = __expf((sT[kt][r]     - mn) * 0.125f);
                float p1 = __expf((sT[kt][r + 1] - mn) * 0.125f);
                sum += p0 + p1;
                float s0 = p0 * 512.0f, s1 = p1 * 512.0f;   // exact pow2 pre-scale
                _Float16 h0 = (_Float16)s0, h1 = (_Float16)s1;
                f16x2 hp = {h0, h1};
                f16x2 lp = {(_Float16)(s0 - (float)h0), (_Float16)(s1 - (float)h1)};
                const int poff = ln * 72 + kt * 16 + quad * 4 + r;
                *(f16x2*)(&PTh[w][poff]) = hp;
                *(f16x2*)(&PTl[w][poff]) = lp;
            }
        }
        sum += __shfl_xor(sum, 16);
        sum += __shfl_xor(sum, 32);
        l_run = l_run * a + sum;

#pragma unroll
        for (int dt = 0; dt < 4; ++dt) {
            O[dt][0] *= a; O[dt][1] *= a; O[dt][2] *= a; O[dt][3] *= a;
        }

        // ---- O^T += V^T P^T (wave-private PT: NO barrier needed) ----
        __builtin_amdgcn_s_setprio(1);
#pragma unroll
        for (int ks2 = 0; ks2 < 2; ++ks2) {
            f16x8 ph = *(const f16x8*)(&PTh[w][ln * 72 + ks2 * 32 + quad * 8]);
            f16x8 pl = *(const f16x8*)(&PTl[w][ln * 72 + ks2 * 32 + quad * 8]);
#pragma unroll
            for (int dt = 0; dt < 4; ++dt) {
                const int off = (dt * 16 + ln) * 72 + ks2 * 32 + quad * 8;
                f16x8 vh = *(const f16x8*)(VsH + off);
                f16x8 vl = *(const f16x8*)(VsL + off);
                O[dt] = MFMA16(vh, pl, O[dt]);
                O[dt] = MFMA16(vl, ph, O[dt]);
                O[dt] = MFMA16(vh, ph, O[dt]);
            }
        }
        __builtin_amdgcn_s_setprio(0);
    }

    // ---- epilogue: O^T[d][q=ln] -> xbuf rows, 4 coalesced float4/lane ----
    const float inv = 1.0f / (512.0f * l_run);
    const long base = ((long)(b * 2048 + q0 + w * 16 + ln)) * 512 + h * 64 + quad * 4;
#pragma unroll
    for (int dt = 0; dt < 4; ++dt) {
        float4 o;
        o.x = O[dt][0] * inv; o.y = O[dt][1] * inv;
        o.z = O[dt][2] * inv; o.w = O[dt][3] * inv;
        *(float4*)(xbuf + base + dt * 16) = o;
    }
}

// ---------------------------------------------------------------------------
// Kernel 5: final GEMM on the f16 MFMA pipe.  UNCHANGED (green R12).
// ---------------------------------------------------------------------------
__global__ __launch_bounds__(256) void final_mfma(
    const _Float16* __restrict__ qX, const _Float16* __restrict__ WhT,
    const _Float16* __restrict__ WlT, const double* __restrict__ sx,
    float* __restrict__ out)
{
    const int m0 = blockIdx.x * 64, n0 = blockIdx.y * 64;
    const int tid = threadIdx.x;
    const int w = tid >> 6, lane = tid & 63;
    const int ln = lane & 15, quad = lane >> 4;

    __shared__ __align__(16) _Float16 As[64 * 72];
    __shared__ __align__(16) _Float16 BhS[64 * 72];
    __shared__ __align__(16) _Float16 BlS[64 * 72];
    const int srow = tid >> 3, scs = (tid & 7) * 8;

    f32x4 c[4];
#pragma unroll
    for (int nt = 0; nt < 4; ++nt) { c[nt][0] = 0; c[nt][1] = 0; c[nt][2] = 0; c[nt][3] = 0; }

    f16x8 a0, a1, h0, h1, l0, l1;
    a0 = *(const f16x8*)(qX + (long)(m0 + srow) * 512 + scs);
    a1 = *(const f16x8*)(qX + (long)(m0 + 32 + srow) * 512 + scs);
    h0 = *(const f16x8*)(WhT + (long)(n0 + srow) * 512 + scs);
    h1 = *(const f16x8*)(WhT + (long)(n0 + 32 + srow) * 512 + scs);
    l0 = *(const f16x8*)(WlT + (long)(n0 + srow) * 512 + scs);
    l1 = *(const f16x8*)(WlT + (long)(n0 + 32 + srow) * 512 + scs);

    for (int k0 = 0; k0 < 512; k0 += 64) {
        __syncthreads();
        *(f16x8*)(As + srow * 72 + scs) = a0;
        *(f16x8*)(As + (32 + srow) * 72 + scs) = a1;
        *(f16x8*)(BhS + srow * 72 + scs) = h0;
        *(f16x8*)(BhS + (32 + srow) * 72 + scs) = h1;
        *(f16x8*)(BlS + srow * 72 + scs) = l0;
        *(f16x8*)(BlS + (32 + srow) * 72 + scs) = l1;
        __syncthreads();
        if (k0 + 64 < 512) {
            a0 = *(const f16x8*)(qX + (long)(m0 + srow) * 512 + k0 + 64 + scs);
            a1 = *(const f16x8*)(qX + (long)(m0 + 32 + srow) * 512 + k0 + 64 + scs);
            h0 = *(const f16x8*)(WhT + (long)(n0 + srow) * 512 + k0 + 64 + scs);
            h1 = *(const f16x8*)(WhT + (long)(n0 + 32 + srow) * 512 + k0 + 64 + scs);
            l0 = *(const f16x8*)(WlT + (long)(n0 + srow) * 512 + k0 + 64 + scs);
            l1 = *(const f16x8*)(WlT + (long)(n0 + 32 + srow) * 512 + k0 + 64 + scs);
        }
#pragma unroll
        for (int ks = 0; ks < 2; ++ks) {
            f16x8 aF = *(const f16x8*)(As + (w * 16 + ln) * 72 + ks * 32 + quad * 8);
#pragma unroll
            for (int nt = 0; nt < 4; ++nt) {
                const int off = (nt * 16 + ln) * 72 + ks * 32 + quad * 8;
                f16x8 bh = *(const f16x8*)(BhS + off);
                f16x8 bl = *(const f16x8*)(BlS + off);
                c[nt] = MFMA16(aF, bl, c[nt]);
                c[nt] = MFMA16(aF, bh, c[nt]);
            }
        }
    }

#pragma unroll
    for (int nt = 0; nt < 4; ++nt)
#pragma unroll
        for (int r = 0; r < 4; ++r) {
            int m = m0 + w * 16 + quad * 4 + r;
            int n = n0 + nt * 16 + ln;
            out[(long)m * 512 + n] = (float)((double)c[nt][r] * sx[m & 2047]);
        }
}

// ---------------------------------------------------------------------------
extern "C" void kernel_launch(void* const* d_in, const int* in_sizes, int n_in,
                              void* d_out, int out_size, void* d_ws, size_t ws_size,
                              hipStream_t stream)
{
    const float* query = (const float*)d_in[0];
    const float* key_  = (const float*)d_in[1];
    const float* value = (const float*)d_in[2];
    const float* Wq = (const float*)d_in[3];
    const float* Wk = (const float*)d_in[4];
    const float* Wv = (const float*)d_in[5];
    const float* Wf = (const float*)d_in[6];
    float* out = (float*)d_out;

    // workspace carve-up: ~70 MB
    char* p = (char*)d_ws;
    auto alloc = [&](size_t bytes) -> char* {
        char* r = p;
        p += (bytes + 255) & ~(size_t)255;
        return r;
    };
    double*   sA   = (double*)alloc(3 * 2048 * 8);
    double*   sx   = (double*)alloc(2048 * 8);
    double*   sw   = (double*)alloc(3 * 512 * 8);
    _Float16* qW   = (_Float16*)alloc((size_t)3 * 512 * 512 * 2);
    const long PE  = (long)8 * 2048 * 64;   // halfs per slot-plane
    _Float16* Qh   = (_Float16*)alloc((size_t)2 * PE * 2);
    _Float16* Ql   = (_Float16*)alloc((size_t)2 * PE * 2);
    _Float16* Kh   = (_Float16*)alloc((size_t)2 * PE * 2);
    _Float16* Kl   = (_Float16*)alloc((size_t)2 * PE * 2);
    _Float16* Vh   = (_Float16*)alloc((size_t)2 * PE * 2);
    _Float16* Vl   = (_Float16*)alloc((size_t)2 * PE * 2);
    float*    xbuf = (float*)alloc((size_t)8192 * 512 * 4);
    _Float16* qA   = (_Float16*)alloc((size_t)3 * 4 * 2048 * 512 * 2);  // also reused as qX
    _Float16* WhT  = (_Float16*)alloc((size_t)512 * 512 * 2);
    _Float16* WlT  = (_Float16*)alloc((size_t)512 * 512 * 2);

    token_scale<<<dim3(2048, 3), 256, 0, stream>>>(query, key_, value, sA);
    wquant<<<dim3(8, 3), 256, 0, stream>>>(Wq, Wk, Wv, sw, qW);
    aquant<<<dim3(2048, 3), 256, 0, stream>>>(query, key_, value, sA, qA);
    wfsplit<<<dim3(8, 8), 256, 0, stream>>>(Wf, WhT, WlT);
    for (int pair = 0; pair < 2; ++pair) {
        proj_mfma<<<dim3(32, 8, 3), 256, 0, stream>>>(qA, qW, sA, sw,
            Qh, Ql, Kh, Kl, Vh, Vl, pair * 2);
        proj_mfma<<<dim3(32, 8, 3), 256, 0, stream>>>(qA, qW, sA, sw,
            Qh + PE, Ql + PE, Kh + PE, Kl + PE, Vh + PE, Vl + PE, pair * 2 + 1);
        attn_mfma<<<dim3(32, 8, 2), 256, 0, stream>>>(Qh, Ql, Kh, Kl, Vh, Vl, xbuf, pair * 2);
    }
    token_scale<<<dim3(2048, 1), 256, 0, stream>>>(xbuf, xbuf, xbuf, sx);
    aquant<<<dim3(2048, 1), 256, 0, stream>>>(xbuf, xbuf, xbuf, sx, qA);  // qX alias
    final_mfma<<<dim3(128, 8), 256, 0, stream>>>(qA, WhT, WlT, sx, out);
}